// Round 11
// baseline (313.580 us; speedup 1.0000x reference)
//
#include <hip/hip_runtime.h>
#include <hip/hip_bf16.h>

// FusionRetrModel: B=4, NL=2 (only l=1 used), P=100, TOK=60, T=6000, D=768.
// R11 pipeline (4 dispatches; gemm_t absorbed into gemm_h via ticket+flag):
//   prep_all: Qpad bf16; Wtb; WpbT (LDS transpose); Wf1 cast; cp/ct GEMV;
//             out init = bf2*msum; sync counters zeroed.
//   mid: [0,1128) gemm_ts: ts = Qpad @ Wtb^T + ct
//        [1128,1272) gemm_wc: Wcomb[b] = Wf1_lo @ Wpb[b]
//        [1272,2040) prep2: bf1x = bf1 + Wf1_lo.cp   (tail-packed)
//   tmax: per-table max over passages (600 rows/batch)
//   gemm_ht: first 120 blocks TO START (ticket) each run one gemm_t tile
//            (Ht = tmax @ Wf1_hi^T, f32) then threadfence+flag; ALL blocks run
//            their gemm_h tile (Hcore = Qpad @ Wcomb^T); epilogue spins on
//            flag==120 (workers long done by then), then H = Hcore +
//            Ht[gather] + bf1x, relu, dot w2, masked per-passage -> atomicAdd.
//            Deadlock-free: tickets go to first-started blocks only; no
//            pre-work spin anywhere.
// All GEMMs: 128^2 tile, BK=64, dbuf 2-phase, T2 swizzle (src-side), 0 conflicts.
// Workspace: ~102 MB (+8B sync).

typedef unsigned short u16;
typedef unsigned int u32;
typedef __attribute__((ext_vector_type(8))) short bf16x8;
typedef __attribute__((ext_vector_type(4))) float f32x4;

#define NUM_TABLES 10
#define MPAD 6016
#define DD 768

__device__ __forceinline__ u16 f2bf(float f) {
  u32 u = __builtin_bit_cast(u32, f);
  u32 r = u + 0x7FFFu + ((u >> 16) & 1u);
  return (u16)(r >> 16);
}
__device__ __forceinline__ float bf2f(u16 h) {
  u32 u = ((u32)h) << 16;
  return __builtin_bit_cast(float, u);
}
__device__ __forceinline__ u32 pack_bf2(float lo, float hi) {
  return (u32)f2bf(lo) | ((u32)f2bf(hi) << 16);
}

__device__ __forceinline__ void gload_lds16(const u16* g, u16* l) {
  __builtin_amdgcn_global_load_lds(
      (const __attribute__((address_space(1))) void*)g,
      (__attribute__((address_space(3))) void*)l, 16, 0, 0);
}

// ---------------- fused prep (one dispatch) ----------------
__global__ void prep_all(const float* __restrict__ qps, uint4* __restrict__ qpad,
                         const float* __restrict__ Ans, const float* __restrict__ Wp,
                         const float* __restrict__ Wt, u16* __restrict__ Wtb,
                         u16* __restrict__ WpbT,
                         const float* __restrict__ Wf1, uint4* __restrict__ Wf1b,
                         const float* __restrict__ bp, const float* __restrict__ bt,
                         float* __restrict__ cp, float* __restrict__ ct,
                         const float* __restrict__ mask, const float* __restrict__ bf2,
                         float* __restrict__ out, u32* __restrict__ sync) {
  int blk = blockIdx.x;
  int tid = threadIdx.x;
  if (blk < 9024) {
    // ---- Qpad: cast l=1 slice to bf16, pad rows [6000,6016) ----
    size_t c = (size_t)blk * 256 + tid;
    const int per_b = MPAD * (DD / 8);
    int b = (int)(c / per_b);
    int rr = (int)(c % per_b);
    int r = rr / (DD / 8);
    int kc = rr % (DD / 8);
    uint4 o;
    if (r < 6000) {
      const float* src = qps + (((size_t)(b * 2 + 1)) * 6000 + r) * DD + kc * 8;
      float4 f0 = *(const float4*)src;
      float4 f1 = *(const float4*)(src + 4);
      o.x = pack_bf2(f0.x, f0.y);
      o.y = pack_bf2(f0.z, f0.w);
      o.z = pack_bf2(f1.x, f1.y);
      o.w = pack_bf2(f1.z, f1.w);
    } else {
      o = make_uint4(0, 0, 0, 0);
    }
    qpad[c] = o;
  } else if (blk < 10176) {
    // ---- Wtb[b][d][k] = Wt[d][768+k] + A[b][k]*Wt[d][1536+k] ----
    size_t c = (size_t)(blk - 9024) * 256 + tid;
    const int per_b = DD * (DD / 8);
    int b = (int)(c / per_b);
    int rr = (int)(c % per_b);
    int d = rr / (DD / 8);
    int k8 = (rr % (DD / 8)) * 8;
    const float* a = Ans + ((size_t)b * 2 + 1) * DD + k8;
    const float* w2r = Wt + (size_t)d * 2304 + 768 + k8;
    const float* w3r = Wt + (size_t)d * 2304 + 1536 + k8;
    float4 a0 = *(const float4*)a, a1 = *(const float4*)(a + 4);
    float4 t20 = *(const float4*)w2r, t21 = *(const float4*)(w2r + 4);
    float4 t30 = *(const float4*)w3r, t31 = *(const float4*)(w3r + 4);
    uint4 o;
    o.x = pack_bf2(t20.x + a0.x * t30.x, t20.y + a0.y * t30.y);
    o.y = pack_bf2(t20.z + a0.z * t30.z, t20.w + a0.w * t30.w);
    o.z = pack_bf2(t21.x + a1.x * t31.x, t21.y + a1.y * t31.y);
    o.w = pack_bf2(t21.z + a1.z * t31.z, t21.w + a1.w * t31.w);
    *(uint4*)(Wtb + ((size_t)b * DD + d) * DD + k8) = o;
  } else if (blk < 10752) {
    // ---- WpbT[b][k][d] = Wp[d][768+k] + A[b][k]*Wp[d][1536+k] (LDS transpose) ----
    int tb = blk - 10176;
    int b = tb / 144;
    int tt = tb % 144;
    int k0 = (tt / 12) * 64, d0 = (tt % 12) * 64;
    __shared__ u16 tile[64][72];
    int kc = tid & 63;
    int r0 = tid >> 6;
    float av = Ans[((size_t)b * 2 + 1) * DD + k0 + kc];
#pragma unroll
    for (int it = 0; it < 16; ++it) {
      int dr = it * 4 + r0;
      const float* wrow = Wp + (size_t)(d0 + dr) * 2304;
      float v = wrow[768 + k0 + kc] + av * wrow[1536 + k0 + kc];
      tile[kc][dr] = f2bf(v);
    }
    __syncthreads();
#pragma unroll
    for (int it = 0; it < 2; ++it) {
      int kk = it * 32 + (tid >> 3);
      int dd = (tid & 7) * 8;
      *(uint4*)(WpbT + ((size_t)b * DD + k0 + kk) * DD + d0 + dd) =
          *(const uint4*)&tile[kk][dd];
    }
  } else if (blk < 11328) {
    // ---- Wf1 cast ----
    size_t c = (size_t)(blk - 10752) * 256 + tid;
    const float* src = Wf1 + c * 8;
    float4 f0 = *(const float4*)src;
    float4 f1 = *(const float4*)(src + 4);
    uint4 o;
    o.x = pack_bf2(f0.x, f0.y);
    o.y = pack_bf2(f0.z, f0.w);
    o.z = pack_bf2(f1.x, f1.y);
    o.w = pack_bf2(f1.z, f1.w);
    Wf1b[c] = o;
  } else if (blk < 12864) {
    // ---- cp/ct parallel: one block per (matrix, d) ----
    int e = blk - 11328;
    int isT = e >= 768;
    int d = e - (isT ? 768 : 0);
    const float* wrow = (isT ? Wt : Wp) + (size_t)d * 2304;
    float a0 = 0.f, a1 = 0.f, a2 = 0.f, a3 = 0.f;
    for (int k = tid; k < DD; k += 256) {
      float w = wrow[k];
      a0 += w * Ans[1 * DD + k];
      a1 += w * Ans[3 * DD + k];
      a2 += w * Ans[5 * DD + k];
      a3 += w * Ans[7 * DD + k];
    }
#pragma unroll
    for (int off = 32; off > 0; off >>= 1) {
      a0 += __shfl_down(a0, off);
      a1 += __shfl_down(a1, off);
      a2 += __shfl_down(a2, off);
      a3 += __shfl_down(a3, off);
    }
    __shared__ float red[4][4];
    int wid = tid >> 6;
    if ((tid & 63) == 0) {
      red[wid][0] = a0; red[wid][1] = a1; red[wid][2] = a2; red[wid][3] = a3;
    }
    __syncthreads();
    if (tid < 4) {
      float s = red[0][tid] + red[1][tid] + red[2][tid] + red[3][tid];
      float bias = (isT ? bt : bp)[d];
      (isT ? ct : cp)[tid * DD + d] = s + bias;
    }
  } else {
    // ---- out init = bf2 * msum; zero sync counters ----
    int idx = (blk - 12864) * 256 + tid;
    if (idx >= 400) {
      if (idx < 402) sync[idx - 400] = 0u;
      return;
    }
    const float* m = mask + (size_t)idx * 60;
    float s = 0.f;
    for (int t = 0; t < 60; ++t) s += m[t];
    out[idx] = bf2[0] * s;
  }
}

// ---------------- mid: gemm_ts | gemm_wc | prep2 (one dispatch) ----------------
__global__ __launch_bounds__(256, 2)
void mid_kernel(const u16* __restrict__ Q, const u16* __restrict__ Wtb,
                const float* __restrict__ ct, u16* __restrict__ ts,
                const u16* __restrict__ Wf1b, const u16* __restrict__ WpbT,
                u16* __restrict__ Wcomb, const float* __restrict__ Wf1,
                const float* __restrict__ cp, const float* __restrict__ bf1,
                float* __restrict__ bf1x) {
  __shared__ u16 As[2][128 * 64];
  __shared__ u16 Bs[2][128 * 64];
  __shared__ float red[4][4];
  int blk = blockIdx.x;
  int tid = threadIdx.x;

  if (blk >= 1272) {
    // ---- prep2: bf1x[b][c] = bf1[c] + Wf1_lo[c,:].cp[b,:] ----
    int c = blk - 1272;
    const float* wrow = Wf1 + (size_t)c * 1536;
    float a0 = 0.f, a1 = 0.f, a2 = 0.f, a3 = 0.f;
    for (int d = tid; d < DD; d += 256) {
      float w = wrow[d];
      a0 += w * cp[0 * DD + d];
      a1 += w * cp[1 * DD + d];
      a2 += w * cp[2 * DD + d];
      a3 += w * cp[3 * DD + d];
    }
#pragma unroll
    for (int off = 32; off > 0; off >>= 1) {
      a0 += __shfl_down(a0, off);
      a1 += __shfl_down(a1, off);
      a2 += __shfl_down(a2, off);
      a3 += __shfl_down(a3, off);
    }
    int wid = tid >> 6;
    if ((tid & 63) == 0) {
      red[wid][0] = a0; red[wid][1] = a1; red[wid][2] = a2; red[wid][3] = a3;
    }
    __syncthreads();
    if (tid < 4) {
      float s = red[0][tid] + red[1][tid] + red[2][tid] + red[3][tid];
      bf1x[tid * DD + c] = bf1[c] + s;
    }
    return;
  }

  const int lane = tid & 63;
  const int wid = tid >> 6;
  const int wm = wid >> 1, wn = wid & 1;
  const int lrow = lane >> 3;
  const int lcol_s = (((lane & 7) ^ (lrow & 7)) * 8);
  const int axor = (lane & 7) << 3;
  f32x4 acc[4][4] = {};

  if (blk < 1128) {
    // ---- gemm_ts: ts = Qpad @ Wtb^T + ct ----
    int lid = (blk & 7) * 141 + (blk >> 3);
    int n = lid % 6;
    int m = (lid / 6) % 47;
    int b = lid / 282;
    const int m0 = m * 128;
    const int n0 = n * 128;

    const u16* Abase = Q + (size_t)b * MPAD * DD;
    const u16* Bbase = Wtb + (size_t)b * DD * DD;

    const u16* aptr[4];
    const u16* bptr[4];
#pragma unroll
    for (int j = 0; j < 4; ++j) {
      aptr[j] = Abase + (size_t)(m0 + wid * 32 + j * 8 + lrow) * DD + lcol_s;
      bptr[j] = Bbase + (size_t)(n0 + wid * 32 + j * 8 + lrow) * DD + lcol_s;
    }
#pragma unroll
    for (int j = 0; j < 4; ++j) {
      gload_lds16(aptr[j], &As[0][(wid * 32 + j * 8) * 64]);
      gload_lds16(bptr[j], &Bs[0][(wid * 32 + j * 8) * 64]);
      aptr[j] += 64; bptr[j] += 64;
    }
    __syncthreads();

    int cur = 0;
    for (int kt = 0; kt < 12; ++kt) {
      if (kt < 11) {
#pragma unroll
        for (int j = 0; j < 4; ++j) {
          gload_lds16(aptr[j], &As[cur ^ 1][(wid * 32 + j * 8) * 64]);
          gload_lds16(bptr[j], &Bs[cur ^ 1][(wid * 32 + j * 8) * 64]);
          aptr[j] += 64; bptr[j] += 64;
        }
      }
      bf16x8 af[2][4], bfr[2][4];
#pragma unroll
      for (int kf = 0; kf < 2; ++kf)
#pragma unroll
        for (int mf = 0; mf < 4; ++mf)
          af[kf][mf] = *(const bf16x8*)&As[cur][(wm * 64 + mf * 16 + (lane & 15)) * 64 + ((kf * 32 + (lane >> 4) * 8) ^ axor)];
#pragma unroll
      for (int kf = 0; kf < 2; ++kf)
#pragma unroll
        for (int nf = 0; nf < 4; ++nf)
          bfr[kf][nf] = *(const bf16x8*)&Bs[cur][(wn * 64 + nf * 16 + (lane & 15)) * 64 + ((kf * 32 + (lane >> 4) * 8) ^ axor)];
#pragma unroll
      for (int mf = 0; mf < 4; ++mf)
#pragma unroll
        for (int nf = 0; nf < 4; ++nf) {
          acc[mf][nf] = __builtin_amdgcn_mfma_f32_16x16x32_bf16(af[0][mf], bfr[0][nf], acc[mf][nf], 0, 0, 0);
          acc[mf][nf] = __builtin_amdgcn_mfma_f32_16x16x32_bf16(af[1][mf], bfr[1][nf], acc[mf][nf], 0, 0, 0);
        }
      __syncthreads();
      cur ^= 1;
    }

    u16* dst = ts + (size_t)b * MPAD * DD;
    const float* cv = ct + b * DD;
#pragma unroll
    for (int mf = 0; mf < 4; ++mf)
#pragma unroll
      for (int nf = 0; nf < 4; ++nf)
#pragma unroll
        for (int r = 0; r < 4; ++r) {
          int row = m0 + wm * 64 + mf * 16 + (lane >> 4) * 4 + r;
          int col = n0 + wn * 64 + nf * 16 + (lane & 15);
          dst[(size_t)row * DD + col] = f2bf(acc[mf][nf][r] + cv[col]);
        }
  } else {
    // ---- gemm_wc: Wcomb[b][c][k] = sum_d Wf1_lo[c][d] * WpbT[b][k][d] ----
    int f = blk - 1128;
    int lid = (f & 7) * 18 + (f >> 3);
    int n = lid % 6;
    int m = (lid / 6) % 6;
    int b = lid / 36;
    const int m0 = m * 128;
    const int n0 = n * 128;

    const u16* Bbase = WpbT + (size_t)b * DD * DD;
    const u16* aptr[4];
    const u16* bptr[4];
#pragma unroll
    for (int j = 0; j < 4; ++j) {
      aptr[j] = Wf1b + (size_t)(m0 + wid * 32 + j * 8 + lrow) * 1536 + lcol_s;
      bptr[j] = Bbase + (size_t)(n0 + wid * 32 + j * 8 + lrow) * DD + lcol_s;
    }
#pragma unroll
    for (int j = 0; j < 4; ++j) {
      gload_lds16(aptr[j], &As[0][(wid * 32 + j * 8) * 64]);
      gload_lds16(bptr[j], &Bs[0][(wid * 32 + j * 8) * 64]);
      aptr[j] += 64; bptr[j] += 64;
    }
    __syncthreads();

    int cur = 0;
    for (int kt = 0; kt < 12; ++kt) {
      if (kt < 11) {
#pragma unroll
        for (int j = 0; j < 4; ++j) {
          gload_lds16(aptr[j], &As[cur ^ 1][(wid * 32 + j * 8) * 64]);
          gload_lds16(bptr[j], &Bs[cur ^ 1][(wid * 32 + j * 8) * 64]);
          aptr[j] += 64; bptr[j] += 64;
        }
      }
      bf16x8 af[2][4], bfr[2][4];
#pragma unroll
      for (int kf = 0; kf < 2; ++kf)
#pragma unroll
        for (int mf = 0; mf < 4; ++mf)
          af[kf][mf] = *(const bf16x8*)&As[cur][(wm * 64 + mf * 16 + (lane & 15)) * 64 + ((kf * 32 + (lane >> 4) * 8) ^ axor)];
#pragma unroll
      for (int kf = 0; kf < 2; ++kf)
#pragma unroll
        for (int nf = 0; nf < 4; ++nf)
          bfr[kf][nf] = *(const bf16x8*)&Bs[cur][(wn * 64 + nf * 16 + (lane & 15)) * 64 + ((kf * 32 + (lane >> 4) * 8) ^ axor)];
#pragma unroll
      for (int mf = 0; mf < 4; ++mf)
#pragma unroll
        for (int nf = 0; nf < 4; ++nf) {
          acc[mf][nf] = __builtin_amdgcn_mfma_f32_16x16x32_bf16(af[0][mf], bfr[0][nf], acc[mf][nf], 0, 0, 0);
          acc[mf][nf] = __builtin_amdgcn_mfma_f32_16x16x32_bf16(af[1][mf], bfr[1][nf], acc[mf][nf], 0, 0, 0);
        }
      __syncthreads();
      cur ^= 1;
    }

    u16* Cb = Wcomb + (size_t)b * DD * DD;
#pragma unroll
    for (int mf = 0; mf < 4; ++mf)
#pragma unroll
      for (int nf = 0; nf < 4; ++nf)
#pragma unroll
        for (int r = 0; r < 4; ++r) {
          int row = m0 + wm * 64 + mf * 16 + (lane >> 4) * 4 + r;
          int col = n0 + wn * 64 + nf * 16 + (lane & 15);
          Cb[(size_t)row * DD + col] = f2bf(acc[mf][nf][r]);
        }
  }
}

// ---------------- table max ----------------
__global__ void table_max_kernel(const u16* __restrict__ ts, const int* __restrict__ ids,
                                 u16* __restrict__ tmax) {
  int bi = blockIdx.x;  // 720
  int b = bi / 180;
  int rem = bi % 180;
  int tok = rem / 3;
  int dc = rem % 3;
  int d = dc * 256 + threadIdx.x;
  __shared__ int sids[100];
  if (threadIdx.x < 100) sids[threadIdx.x] = ids[b * 100 + threadIdx.x];
  __syncthreads();
  float m[NUM_TABLES];
#pragma unroll
  for (int t = 0; t < NUM_TABLES; ++t) m[t] = -INFINITY;
  const u16* base = ts + ((size_t)b * MPAD + tok) * DD + d;
  for (int p = 0; p < 100; ++p) {
    float v = bf2f(base[(size_t)p * 60 * DD]);
    int id = sids[p];
#pragma unroll
    for (int t = 0; t < NUM_TABLES; ++t)
      if (id == t) m[t] = fmaxf(m[t], v);
  }
#pragma unroll
  for (int t = 0; t < NUM_TABLES; ++t)
    tmax[(((size_t)b * NUM_TABLES + t) * 60 + tok) * DD + d] = f2bf(m[t]);
}

// ---------------- gemm_ht: [ticket<120: gemm_t tile] + gemm_h tile ----------------
__global__ __launch_bounds__(256, 2)
void gemm_ht(const u16* __restrict__ Q, const u16* __restrict__ tmax,
             const u16* __restrict__ Wf1b, float* __restrict__ Ht,
             const int* __restrict__ ids, const u16* __restrict__ Wcomb,
             const float* __restrict__ bf1x, const float* __restrict__ w2,
             const float* __restrict__ mask, float* __restrict__ out,
             u32* __restrict__ sync) {
  __shared__ u16 As[2][128 * 64];
  __shared__ u16 Bs[2][128 * 64];
  __shared__ int sids[100];
  __shared__ float pacc[4];
  __shared__ u32 tkt;
  const int tid = threadIdx.x;
  const int lane = tid & 63;
  const int wid = tid >> 6;
  const int wm = wid >> 1, wn = wid & 1;
  const int lrow = lane >> 3;
  const int lcol_s = (((lane & 7) ^ (lrow & 7)) * 8);
  const int axor = (lane & 7) << 3;

  if (tid == 0) tkt = atomicAdd(&sync[0], 1u);
  __syncthreads();
  const u32 myt = tkt;

  if (myt < 120) {
    // ---- gemm_t tile myt: Ht = tmax @ Wf1_hi^T (f32 out) ----
    int lid = (myt & 7) * 15 + (myt >> 3);
    int n = lid % 6;
    int m = (lid / 6) % 5;
    int b = lid / 30;
    const int m0 = m * 128;
    const int n0 = n * 128;

    const u16* Abase = tmax + (size_t)b * 600 * DD;
    f32x4 acc[4][4] = {};
    const u16* aptr[4];
    const u16* bptr[4];
#pragma unroll
    for (int j = 0; j < 4; ++j) {
      int row = m0 + wid * 32 + j * 8 + lrow;
      int rp = row < 600 ? row : 599;
      aptr[j] = Abase + (size_t)rp * DD + lcol_s;
      bptr[j] = Wf1b + (size_t)(n0 + wid * 32 + j * 8 + lrow) * 1536 + 768 + lcol_s;
    }
#pragma unroll
    for (int j = 0; j < 4; ++j) {
      gload_lds16(aptr[j], &As[0][(wid * 32 + j * 8) * 64]);
      gload_lds16(bptr[j], &Bs[0][(wid * 32 + j * 8) * 64]);
      aptr[j] += 64; bptr[j] += 64;
    }
    __syncthreads();

    int cur = 0;
    for (int kt = 0; kt < 12; ++kt) {
      if (kt < 11) {
#pragma unroll
        for (int j = 0; j < 4; ++j) {
          gload_lds16(aptr[j], &As[cur ^ 1][(wid * 32 + j * 8) * 64]);
          gload_lds16(bptr[j], &Bs[cur ^ 1][(wid * 32 + j * 8) * 64]);
          aptr[j] += 64; bptr[j] += 64;
        }
      }
      bf16x8 af[2][4], bfr[2][4];
#pragma unroll
      for (int kf = 0; kf < 2; ++kf)
#pragma unroll
        for (int mf = 0; mf < 4; ++mf)
          af[kf][mf] = *(const bf16x8*)&As[cur][(wm * 64 + mf * 16 + (lane & 15)) * 64 + ((kf * 32 + (lane >> 4) * 8) ^ axor)];
#pragma unroll
      for (int kf = 0; kf < 2; ++kf)
#pragma unroll
        for (int nf = 0; nf < 4; ++nf)
          bfr[kf][nf] = *(const bf16x8*)&Bs[cur][(wn * 64 + nf * 16 + (lane & 15)) * 64 + ((kf * 32 + (lane >> 4) * 8) ^ axor)];
#pragma unroll
      for (int mf = 0; mf < 4; ++mf)
#pragma unroll
        for (int nf = 0; nf < 4; ++nf) {
          acc[mf][nf] = __builtin_amdgcn_mfma_f32_16x16x32_bf16(af[0][mf], bfr[0][nf], acc[mf][nf], 0, 0, 0);
          acc[mf][nf] = __builtin_amdgcn_mfma_f32_16x16x32_bf16(af[1][mf], bfr[1][nf], acc[mf][nf], 0, 0, 0);
        }
      __syncthreads();
      cur ^= 1;
    }

    float* Hb = Ht + (size_t)b * 640 * DD;
#pragma unroll
    for (int mf = 0; mf < 4; ++mf)
#pragma unroll
      for (int nf = 0; nf < 4; ++nf)
#pragma unroll
        for (int r = 0; r < 4; ++r) {
          int row = m0 + wm * 64 + mf * 16 + (lane >> 4) * 4 + r;
          int col = n0 + wn * 64 + nf * 16 + (lane & 15);
          Hb[(size_t)row * DD + col] = acc[mf][nf][r];
        }
    __threadfence();
    __syncthreads();  // all lanes' stores issued before flag
    if (tid == 0) atomicAdd(&sync[1], 1u);
  }

  // ---- gemm_h tile = blockIdx.x ----
  {
    int blk = blockIdx.x;
    int lid = (blk & 7) * 141 + (blk >> 3);
    int n = lid % 6;
    int m = (lid / 6) % 47;
    int b = lid / 282;
    const int m0 = m * 128;
    const int n0 = n * 128;

    if (tid < 100) sids[tid] = ids[b * 100 + tid];
    if (tid < 4) pacc[tid] = 0.f;

    const u16* Abase = Q + (size_t)b * MPAD * DD;
    const u16* Bbase = Wcomb + (size_t)b * DD * DD;

    f32x4 acc[4][4] = {};
    const u16* aptr[4];
    const u16* bptr[4];
#pragma unroll
    for (int j = 0; j < 4; ++j) {
      aptr[j] = Abase + (size_t)(m0 + wid * 32 + j * 8 + lrow) * DD + lcol_s;
      bptr[j] = Bbase + (size_t)(n0 + wid * 32 + j * 8 + lrow) * DD + lcol_s;
    }
#pragma unroll
    for (int j = 0; j < 4; ++j) {
      gload_lds16(aptr[j], &As[0][(wid * 32 + j * 8) * 64]);
      gload_lds16(bptr[j], &Bs[0][(wid * 32 + j * 8) * 64]);
      aptr[j] += 64; bptr[j] += 64;
    }
    __syncthreads();

    int cur = 0;
    for (int kt = 0; kt < 12; ++kt) {
      if (kt < 11) {
#pragma unroll
        for (int j = 0; j < 4; ++j) {
          gload_lds16(aptr[j], &As[cur ^ 1][(wid * 32 + j * 8) * 64]);
          gload_lds16(bptr[j], &Bs[cur ^ 1][(wid * 32 + j * 8) * 64]);
          aptr[j] += 64; bptr[j] += 64;
        }
      }
      bf16x8 af[2][4], bfr[2][4];
#pragma unroll
      for (int kf = 0; kf < 2; ++kf)
#pragma unroll
        for (int mf = 0; mf < 4; ++mf)
          af[kf][mf] = *(const bf16x8*)&As[cur][(wm * 64 + mf * 16 + (lane & 15)) * 64 + ((kf * 32 + (lane >> 4) * 8) ^ axor)];
#pragma unroll
      for (int kf = 0; kf < 2; ++kf)
#pragma unroll
        for (int nf = 0; nf < 4; ++nf)
          bfr[kf][nf] = *(const bf16x8*)&Bs[cur][(wn * 64 + nf * 16 + (lane & 15)) * 64 + ((kf * 32 + (lane >> 4) * 8) ^ axor)];
#pragma unroll
      for (int mf = 0; mf < 4; ++mf)
#pragma unroll
        for (int nf = 0; nf < 4; ++nf) {
          acc[mf][nf] = __builtin_amdgcn_mfma_f32_16x16x32_bf16(af[0][mf], bfr[0][nf], acc[mf][nf], 0, 0, 0);
          acc[mf][nf] = __builtin_amdgcn_mfma_f32_16x16x32_bf16(af[1][mf], bfr[1][nf], acc[mf][nf], 0, 0, 0);
        }
      __syncthreads();
      cur ^= 1;
    }

    // wait for all 120 gemm_t tiles before reading Ht (workers long done)
    if (tid == 0) {
      while (atomicAdd(&sync[1], 0u) < 120u) __builtin_amdgcn_s_sleep(32);
    }
    __syncthreads();
    __threadfence();

    float b1v[4], w2v[4];
    int cbase = n0 + wn * 64 + (lane & 15);
#pragma unroll
    for (int nf = 0; nf < 4; ++nf) {
      b1v[nf] = bf1x[b * DD + cbase + nf * 16];
      w2v[nf] = w2[cbase + nf * 16];
    }
    const float* Hb = Ht + (size_t)b * 640 * DD;
    const int pfirst = m0 / 60;
#pragma unroll
    for (int mf = 0; mf < 4; ++mf)
#pragma unroll
      for (int r = 0; r < 4; ++r) {
        int row = m0 + wm * 64 + mf * 16 + (lane >> 4) * 4 + r;
        if (row < 6000) {
          int p = (unsigned)row / 60u;
          int tok = row - p * 60;
          const float* htrow = Hb + (size_t)(sids[p] * 60 + tok) * DD + cbase;
          float s = 0.f;
#pragma unroll
          for (int nf = 0; nf < 4; ++nf)
            s += fmaxf(acc[mf][nf][r] + htrow[nf * 16] + b1v[nf], 0.f) * w2v[nf];
          s += __shfl_xor(s, 1);
          s += __shfl_xor(s, 2);
          s += __shfl_xor(s, 4);
          s += __shfl_xor(s, 8);
          if ((lane & 15) == 0) {
            float mk = mask[((size_t)b * 100 + p) * 60 + tok];
            atomicAdd(&pacc[p - pfirst], mk * s);
          }
        }
      }
    __syncthreads();
    int plast = (m0 + 127 < 6000 ? m0 + 127 : 5999) / 60;
    if (tid <= plast - pfirst)
      atomicAdd(out + b * 100 + pfirst + tid, pacc[tid]);
  }
}

// ---------------- launch ----------------
extern "C" void kernel_launch(void* const* d_in, const int* in_sizes, int n_in,
                              void* d_out, int out_size, void* d_ws, size_t ws_size,
                              hipStream_t stream) {
  const float* answer = (const float*)d_in[0];
  const float* qps    = (const float*)d_in[1];
  const float* mask   = (const float*)d_in[2];
  const int*   tids   = (const int*)d_in[3];
  const float* Wp     = (const float*)d_in[4];
  const float* bp     = (const float*)d_in[5];
  const float* Wt     = (const float*)d_in[6];
  const float* bt     = (const float*)d_in[7];
  const float* Wf1    = (const float*)d_in[8];
  const float* bf1    = (const float*)d_in[9];
  const float* Wf2    = (const float*)d_in[10];
  const float* bf2    = (const float*)d_in[11];
  float* out = (float*)d_out;

  char* ws = (char*)d_ws;
  // region layout (bytes); total ~102 MB + 8B sync
  u16* Qpad  = (u16*)(ws + 0);            // 36,962,304
  u16* ts    = (u16*)(ws + 36962304);     // 36,962,304
  u16* tmax  = (u16*)(ws + 73924608);     //  3,686,400
  float* Ht  = (float*)(ws + 77611008);   //  7,864,320
  u16* Wtb   = (u16*)(ws + 85475328);     //  4,718,592
  u16* WpbT  = (u16*)(ws + 90193920);     //  4,718,592
  u16* Wcomb = (u16*)(ws + 94912512);     //  4,718,592
  u16* Wf1b  = (u16*)(ws + 99631104);     //  2,359,296
  float* cp  = (float*)(ws + 101990400);  //     12,288
  float* ct  = (float*)(ws + 102002688);  //     12,288
  float* bf1x= (float*)(ws + 102014976);  //     12,288
  u32* sync  = (u32*)(ws + 102027264);    //          8

  prep_all<<<12866, 256, 0, stream>>>(qps, (uint4*)Qpad, answer, Wp, Wt, Wtb, WpbT,
                                      Wf1, (uint4*)Wf1b, bp, bt, cp, ct,
                                      mask, bf2, out, sync);

  mid_kernel<<<2040, 256, 0, stream>>>(Qpad, Wtb, ct, ts, Wf1b, WpbT, Wcomb,
                                       Wf1, cp, bf1, bf1x);

  table_max_kernel<<<720, 256, 0, stream>>>(ts, tids, tmax);

  gemm_ht<<<1128, 256, 0, stream>>>(Qpad, tmax, Wf1b, Ht, tids, Wcomb,
                                    bf1x, Wf2, mask, out, sync);
}

// Round 12
// 195.486 us; speedup vs baseline: 1.6041x; 1.6041x over previous
//
#include <hip/hip_runtime.h>
#include <hip/hip_bf16.h>

// FusionRetrModel: B=4, NL=2 (only l=1 used), P=100, TOK=60, T=6000, D=768.
// R12 pipeline (R10 revert + packing fixes; R11's ticket/spin removed — 2nd
// confirmation that cross-block atomic sync is ~3x penalized on this chip):
//   prep_all: Qpad bf16; Wtb; WpbT (LDS transpose); Wf1 cast; cp/ct GEMV;
//             out init = bf2*msum.
//   mid (wc FIRST so its round hides under gemm_ts; prep2 pads the tail):
//     [0,144)     gemm_wc: Wcomb[b] = Wf1_lo @ Wpb[b] (via WpbT)
//     [144,1272)  gemm_ts: ts = Qpad @ Wtb^T + ct
//     [1272,2040) prep2: bf1x = bf1 + Wf1_lo.cp
//   tmax:   per-table max over passages (600 rows/batch)
//   gemm_t: Ht = tmax @ Wf1_hi^T (f32, M=640 pad)
//   gemm_h: 128x96 tiles (1504 blocks = 2.94 rounds, kills the 20%-full tail
//           round of the 128^2/1128-block version). Hcore = Qpad @ Wcomb^T;
//           epilogue H = Hcore + Ht[gather] + bf1x, relu, dot w2, masked
//           per-passage reduce -> atomicAdd out.
// GEMMs: BK=64, dbuf 2-phase, T2 swizzle (src-side), 0 bank conflicts.
// Workspace: ~102 MB.

typedef unsigned short u16;
typedef unsigned int u32;
typedef __attribute__((ext_vector_type(8))) short bf16x8;
typedef __attribute__((ext_vector_type(4))) float f32x4;

#define NUM_TABLES 10
#define MPAD 6016
#define DD 768

__device__ __forceinline__ u16 f2bf(float f) {
  u32 u = __builtin_bit_cast(u32, f);
  u32 r = u + 0x7FFFu + ((u >> 16) & 1u);
  return (u16)(r >> 16);
}
__device__ __forceinline__ float bf2f(u16 h) {
  u32 u = ((u32)h) << 16;
  return __builtin_bit_cast(float, u);
}
__device__ __forceinline__ u32 pack_bf2(float lo, float hi) {
  return (u32)f2bf(lo) | ((u32)f2bf(hi) << 16);
}

__device__ __forceinline__ void gload_lds16(const u16* g, u16* l) {
  __builtin_amdgcn_global_load_lds(
      (const __attribute__((address_space(1))) void*)g,
      (__attribute__((address_space(3))) void*)l, 16, 0, 0);
}

// ---------------- fused prep (one dispatch) ----------------
__global__ void prep_all(const float* __restrict__ qps, uint4* __restrict__ qpad,
                         const float* __restrict__ Ans, const float* __restrict__ Wp,
                         const float* __restrict__ Wt, u16* __restrict__ Wtb,
                         u16* __restrict__ WpbT,
                         const float* __restrict__ Wf1, uint4* __restrict__ Wf1b,
                         const float* __restrict__ bp, const float* __restrict__ bt,
                         float* __restrict__ cp, float* __restrict__ ct,
                         const float* __restrict__ mask, const float* __restrict__ bf2,
                         float* __restrict__ out) {
  int blk = blockIdx.x;
  int tid = threadIdx.x;
  if (blk < 9024) {
    // ---- Qpad: cast l=1 slice to bf16, pad rows [6000,6016) ----
    size_t c = (size_t)blk * 256 + tid;
    const int per_b = MPAD * (DD / 8);
    int b = (int)(c / per_b);
    int rr = (int)(c % per_b);
    int r = rr / (DD / 8);
    int kc = rr % (DD / 8);
    uint4 o;
    if (r < 6000) {
      const float* src = qps + (((size_t)(b * 2 + 1)) * 6000 + r) * DD + kc * 8;
      float4 f0 = *(const float4*)src;
      float4 f1 = *(const float4*)(src + 4);
      o.x = pack_bf2(f0.x, f0.y);
      o.y = pack_bf2(f0.z, f0.w);
      o.z = pack_bf2(f1.x, f1.y);
      o.w = pack_bf2(f1.z, f1.w);
    } else {
      o = make_uint4(0, 0, 0, 0);
    }
    qpad[c] = o;
  } else if (blk < 10176) {
    // ---- Wtb[b][d][k] = Wt[d][768+k] + A[b][k]*Wt[d][1536+k] ----
    size_t c = (size_t)(blk - 9024) * 256 + tid;
    const int per_b = DD * (DD / 8);
    int b = (int)(c / per_b);
    int rr = (int)(c % per_b);
    int d = rr / (DD / 8);
    int k8 = (rr % (DD / 8)) * 8;
    const float* a = Ans + ((size_t)b * 2 + 1) * DD + k8;
    const float* w2r = Wt + (size_t)d * 2304 + 768 + k8;
    const float* w3r = Wt + (size_t)d * 2304 + 1536 + k8;
    float4 a0 = *(const float4*)a, a1 = *(const float4*)(a + 4);
    float4 t20 = *(const float4*)w2r, t21 = *(const float4*)(w2r + 4);
    float4 t30 = *(const float4*)w3r, t31 = *(const float4*)(w3r + 4);
    uint4 o;
    o.x = pack_bf2(t20.x + a0.x * t30.x, t20.y + a0.y * t30.y);
    o.y = pack_bf2(t20.z + a0.z * t30.z, t20.w + a0.w * t30.w);
    o.z = pack_bf2(t21.x + a1.x * t31.x, t21.y + a1.y * t31.y);
    o.w = pack_bf2(t21.z + a1.z * t31.z, t21.w + a1.w * t31.w);
    *(uint4*)(Wtb + ((size_t)b * DD + d) * DD + k8) = o;
  } else if (blk < 10752) {
    // ---- WpbT[b][k][d] = Wp[d][768+k] + A[b][k]*Wp[d][1536+k] (LDS transpose) ----
    int tb = blk - 10176;
    int b = tb / 144;
    int tt = tb % 144;
    int k0 = (tt / 12) * 64, d0 = (tt % 12) * 64;
    __shared__ u16 tile[64][72];
    int kc = tid & 63;
    int r0 = tid >> 6;
    float av = Ans[((size_t)b * 2 + 1) * DD + k0 + kc];
#pragma unroll
    for (int it = 0; it < 16; ++it) {
      int dr = it * 4 + r0;
      const float* wrow = Wp + (size_t)(d0 + dr) * 2304;
      float v = wrow[768 + k0 + kc] + av * wrow[1536 + k0 + kc];
      tile[kc][dr] = f2bf(v);
    }
    __syncthreads();
#pragma unroll
    for (int it = 0; it < 2; ++it) {
      int kk = it * 32 + (tid >> 3);
      int dd = (tid & 7) * 8;
      *(uint4*)(WpbT + ((size_t)b * DD + k0 + kk) * DD + d0 + dd) =
          *(const uint4*)&tile[kk][dd];
    }
  } else if (blk < 11328) {
    // ---- Wf1 cast ----
    size_t c = (size_t)(blk - 10752) * 256 + tid;
    const float* src = Wf1 + c * 8;
    float4 f0 = *(const float4*)src;
    float4 f1 = *(const float4*)(src + 4);
    uint4 o;
    o.x = pack_bf2(f0.x, f0.y);
    o.y = pack_bf2(f0.z, f0.w);
    o.z = pack_bf2(f1.x, f1.y);
    o.w = pack_bf2(f1.z, f1.w);
    Wf1b[c] = o;
  } else if (blk < 12864) {
    // ---- cp/ct parallel: one block per (matrix, d) ----
    int e = blk - 11328;
    int isT = e >= 768;
    int d = e - (isT ? 768 : 0);
    const float* wrow = (isT ? Wt : Wp) + (size_t)d * 2304;
    float a0 = 0.f, a1 = 0.f, a2 = 0.f, a3 = 0.f;
    for (int k = tid; k < DD; k += 256) {
      float w = wrow[k];
      a0 += w * Ans[1 * DD + k];
      a1 += w * Ans[3 * DD + k];
      a2 += w * Ans[5 * DD + k];
      a3 += w * Ans[7 * DD + k];
    }
#pragma unroll
    for (int off = 32; off > 0; off >>= 1) {
      a0 += __shfl_down(a0, off);
      a1 += __shfl_down(a1, off);
      a2 += __shfl_down(a2, off);
      a3 += __shfl_down(a3, off);
    }
    __shared__ float red[4][4];
    int wid = tid >> 6;
    if ((tid & 63) == 0) {
      red[wid][0] = a0; red[wid][1] = a1; red[wid][2] = a2; red[wid][3] = a3;
    }
    __syncthreads();
    if (tid < 4) {
      float s = red[0][tid] + red[1][tid] + red[2][tid] + red[3][tid];
      float bias = (isT ? bt : bp)[d];
      (isT ? ct : cp)[tid * DD + d] = s + bias;
    }
  } else {
    // ---- out init = bf2 * msum ----
    int idx = (blk - 12864) * 256 + tid;
    if (idx >= 400) return;
    const float* m = mask + (size_t)idx * 60;
    float s = 0.f;
    for (int t = 0; t < 60; ++t) s += m[t];
    out[idx] = bf2[0] * s;
  }
}

// ---------------- mid: gemm_wc | gemm_ts | prep2 (one dispatch; wc first) ----------------
__global__ __launch_bounds__(256, 2)
void mid_kernel(const u16* __restrict__ Q, const u16* __restrict__ Wtb,
                const float* __restrict__ ct, u16* __restrict__ ts,
                const u16* __restrict__ Wf1b, const u16* __restrict__ WpbT,
                u16* __restrict__ Wcomb, const float* __restrict__ Wf1,
                const float* __restrict__ cp, const float* __restrict__ bf1,
                float* __restrict__ bf1x) {
  __shared__ u16 As[2][128 * 64];
  __shared__ u16 Bs[2][128 * 64];
  __shared__ float red[4][4];
  int blk = blockIdx.x;
  int tid = threadIdx.x;

  if (blk >= 1272) {
    // ---- prep2: bf1x[b][c] = bf1[c] + Wf1_lo[c,:].cp[b,:] ----
    int c = blk - 1272;
    const float* wrow = Wf1 + (size_t)c * 1536;
    float a0 = 0.f, a1 = 0.f, a2 = 0.f, a3 = 0.f;
    for (int d = tid; d < DD; d += 256) {
      float w = wrow[d];
      a0 += w * cp[0 * DD + d];
      a1 += w * cp[1 * DD + d];
      a2 += w * cp[2 * DD + d];
      a3 += w * cp[3 * DD + d];
    }
#pragma unroll
    for (int off = 32; off > 0; off >>= 1) {
      a0 += __shfl_down(a0, off);
      a1 += __shfl_down(a1, off);
      a2 += __shfl_down(a2, off);
      a3 += __shfl_down(a3, off);
    }
    int wid = tid >> 6;
    if ((tid & 63) == 0) {
      red[wid][0] = a0; red[wid][1] = a1; red[wid][2] = a2; red[wid][3] = a3;
    }
    __syncthreads();
    if (tid < 4) {
      float s = red[0][tid] + red[1][tid] + red[2][tid] + red[3][tid];
      bf1x[tid * DD + c] = bf1[c] + s;
    }
    return;
  }

  const int lane = tid & 63;
  const int wid = tid >> 6;
  const int wm = wid >> 1, wn = wid & 1;
  const int lrow = lane >> 3;
  const int lcol_s = (((lane & 7) ^ (lrow & 7)) * 8);
  const int axor = (lane & 7) << 3;
  f32x4 acc[4][4] = {};

  if (blk >= 144) {
    // ---- gemm_ts: ts = Qpad @ Wtb^T + ct ----
    int g = blk - 144;
    int lid = (g & 7) * 141 + (g >> 3);
    int n = lid % 6;
    int m = (lid / 6) % 47;
    int b = lid / 282;
    const int m0 = m * 128;
    const int n0 = n * 128;

    const u16* Abase = Q + (size_t)b * MPAD * DD;
    const u16* Bbase = Wtb + (size_t)b * DD * DD;

    const u16* aptr[4];
    const u16* bptr[4];
#pragma unroll
    for (int j = 0; j < 4; ++j) {
      aptr[j] = Abase + (size_t)(m0 + wid * 32 + j * 8 + lrow) * DD + lcol_s;
      bptr[j] = Bbase + (size_t)(n0 + wid * 32 + j * 8 + lrow) * DD + lcol_s;
    }
#pragma unroll
    for (int j = 0; j < 4; ++j) {
      gload_lds16(aptr[j], &As[0][(wid * 32 + j * 8) * 64]);
      gload_lds16(bptr[j], &Bs[0][(wid * 32 + j * 8) * 64]);
      aptr[j] += 64; bptr[j] += 64;
    }
    __syncthreads();

    int cur = 0;
    for (int kt = 0; kt < 12; ++kt) {
      if (kt < 11) {
#pragma unroll
        for (int j = 0; j < 4; ++j) {
          gload_lds16(aptr[j], &As[cur ^ 1][(wid * 32 + j * 8) * 64]);
          gload_lds16(bptr[j], &Bs[cur ^ 1][(wid * 32 + j * 8) * 64]);
          aptr[j] += 64; bptr[j] += 64;
        }
      }
      bf16x8 af[2][4], bfr[2][4];
#pragma unroll
      for (int kf = 0; kf < 2; ++kf)
#pragma unroll
        for (int mf = 0; mf < 4; ++mf)
          af[kf][mf] = *(const bf16x8*)&As[cur][(wm * 64 + mf * 16 + (lane & 15)) * 64 + ((kf * 32 + (lane >> 4) * 8) ^ axor)];
#pragma unroll
      for (int kf = 0; kf < 2; ++kf)
#pragma unroll
        for (int nf = 0; nf < 4; ++nf)
          bfr[kf][nf] = *(const bf16x8*)&Bs[cur][(wn * 64 + nf * 16 + (lane & 15)) * 64 + ((kf * 32 + (lane >> 4) * 8) ^ axor)];
#pragma unroll
      for (int mf = 0; mf < 4; ++mf)
#pragma unroll
        for (int nf = 0; nf < 4; ++nf) {
          acc[mf][nf] = __builtin_amdgcn_mfma_f32_16x16x32_bf16(af[0][mf], bfr[0][nf], acc[mf][nf], 0, 0, 0);
          acc[mf][nf] = __builtin_amdgcn_mfma_f32_16x16x32_bf16(af[1][mf], bfr[1][nf], acc[mf][nf], 0, 0, 0);
        }
      __syncthreads();
      cur ^= 1;
    }

    u16* dst = ts + (size_t)b * MPAD * DD;
    const float* cv = ct + b * DD;
#pragma unroll
    for (int mf = 0; mf < 4; ++mf)
#pragma unroll
      for (int nf = 0; nf < 4; ++nf)
#pragma unroll
        for (int r = 0; r < 4; ++r) {
          int row = m0 + wm * 64 + mf * 16 + (lane >> 4) * 4 + r;
          int col = n0 + wn * 64 + nf * 16 + (lane & 15);
          dst[(size_t)row * DD + col] = f2bf(acc[mf][nf][r] + cv[col]);
        }
  } else {
    // ---- gemm_wc: Wcomb[b][c][k] = sum_d Wf1_lo[c][d] * WpbT[b][k][d] ----
    int f = blk;
    int lid = (f & 7) * 18 + (f >> 3);
    int n = lid % 6;
    int m = (lid / 6) % 6;
    int b = lid / 36;
    const int m0 = m * 128;
    const int n0 = n * 128;

    const u16* Bbase = WpbT + (size_t)b * DD * DD;
    const u16* aptr[4];
    const u16* bptr[4];
#pragma unroll
    for (int j = 0; j < 4; ++j) {
      aptr[j] = Wf1b + (size_t)(m0 + wid * 32 + j * 8 + lrow) * 1536 + lcol_s;
      bptr[j] = Bbase + (size_t)(n0 + wid * 32 + j * 8 + lrow) * DD + lcol_s;
    }
#pragma unroll
    for (int j = 0; j < 4; ++j) {
      gload_lds16(aptr[j], &As[0][(wid * 32 + j * 8) * 64]);
      gload_lds16(bptr[j], &Bs[0][(wid * 32 + j * 8) * 64]);
      aptr[j] += 64; bptr[j] += 64;
    }
    __syncthreads();

    int cur = 0;
    for (int kt = 0; kt < 12; ++kt) {
      if (kt < 11) {
#pragma unroll
        for (int j = 0; j < 4; ++j) {
          gload_lds16(aptr[j], &As[cur ^ 1][(wid * 32 + j * 8) * 64]);
          gload_lds16(bptr[j], &Bs[cur ^ 1][(wid * 32 + j * 8) * 64]);
          aptr[j] += 64; bptr[j] += 64;
        }
      }
      bf16x8 af[2][4], bfr[2][4];
#pragma unroll
      for (int kf = 0; kf < 2; ++kf)
#pragma unroll
        for (int mf = 0; mf < 4; ++mf)
          af[kf][mf] = *(const bf16x8*)&As[cur][(wm * 64 + mf * 16 + (lane & 15)) * 64 + ((kf * 32 + (lane >> 4) * 8) ^ axor)];
#pragma unroll
      for (int kf = 0; kf < 2; ++kf)
#pragma unroll
        for (int nf = 0; nf < 4; ++nf)
          bfr[kf][nf] = *(const bf16x8*)&Bs[cur][(wn * 64 + nf * 16 + (lane & 15)) * 64 + ((kf * 32 + (lane >> 4) * 8) ^ axor)];
#pragma unroll
      for (int mf = 0; mf < 4; ++mf)
#pragma unroll
        for (int nf = 0; nf < 4; ++nf) {
          acc[mf][nf] = __builtin_amdgcn_mfma_f32_16x16x32_bf16(af[0][mf], bfr[0][nf], acc[mf][nf], 0, 0, 0);
          acc[mf][nf] = __builtin_amdgcn_mfma_f32_16x16x32_bf16(af[1][mf], bfr[1][nf], acc[mf][nf], 0, 0, 0);
        }
      __syncthreads();
      cur ^= 1;
    }

    u16* Cb = Wcomb + (size_t)b * DD * DD;
#pragma unroll
    for (int mf = 0; mf < 4; ++mf)
#pragma unroll
      for (int nf = 0; nf < 4; ++nf)
#pragma unroll
        for (int r = 0; r < 4; ++r) {
          int row = m0 + wm * 64 + mf * 16 + (lane >> 4) * 4 + r;
          int col = n0 + wn * 64 + nf * 16 + (lane & 15);
          Cb[(size_t)row * DD + col] = f2bf(acc[mf][nf][r]);
        }
  }
}

// ---------------- table max ----------------
__global__ void table_max_kernel(const u16* __restrict__ ts, const int* __restrict__ ids,
                                 u16* __restrict__ tmax) {
  int bi = blockIdx.x;  // 720
  int b = bi / 180;
  int rem = bi % 180;
  int tok = rem / 3;
  int dc = rem % 3;
  int d = dc * 256 + threadIdx.x;
  __shared__ int sids[100];
  if (threadIdx.x < 100) sids[threadIdx.x] = ids[b * 100 + threadIdx.x];
  __syncthreads();
  float m[NUM_TABLES];
#pragma unroll
  for (int t = 0; t < NUM_TABLES; ++t) m[t] = -INFINITY;
  const u16* base = ts + ((size_t)b * MPAD + tok) * DD + d;
  for (int p = 0; p < 100; ++p) {
    float v = bf2f(base[(size_t)p * 60 * DD]);
    int id = sids[p];
#pragma unroll
    for (int t = 0; t < NUM_TABLES; ++t)
      if (id == t) m[t] = fmaxf(m[t], v);
  }
#pragma unroll
  for (int t = 0; t < NUM_TABLES; ++t)
    tmax[(((size_t)b * NUM_TABLES + t) * 60 + tok) * DD + d] = f2bf(m[t]);
}

// ---------------- gemm_t: Ht = tmax @ Wf1_hi^T (f32 out) ----------------
__global__ __launch_bounds__(256, 2)
void gemm_t(const u16* __restrict__ tmax, const u16* __restrict__ Wf1b,
            float* __restrict__ Ht) {
  int flat = blockIdx.x;   // 120 = 8*15
  int lid = (flat & 7) * 15 + (flat >> 3);
  int n = lid % 6;
  int m = (lid / 6) % 5;
  int b = lid / 30;

  const int m0 = m * 128;
  const int n0 = n * 128;
  const int tid = threadIdx.x;
  const int lane = tid & 63;
  const int wid = tid >> 6;
  const int wm = wid >> 1, wn = wid & 1;

  __shared__ u16 As[2][128 * 64];
  __shared__ u16 Bs[2][128 * 64];

  const u16* Abase = tmax + (size_t)b * 600 * DD;

  f32x4 acc[4][4] = {};

  const int lrow = lane >> 3;
  const int lcol_s = (((lane & 7) ^ (lrow & 7)) * 8);
  const int axor = (lane & 7) << 3;

  const u16* aptr[4];
  const u16* bptr[4];
#pragma unroll
  for (int j = 0; j < 4; ++j) {
    int row = m0 + wid * 32 + j * 8 + lrow;
    int rp = row < 600 ? row : 599;
    aptr[j] = Abase + (size_t)rp * DD + lcol_s;
    bptr[j] = Wf1b + (size_t)(n0 + wid * 32 + j * 8 + lrow) * 1536 + 768 + lcol_s;
  }

#pragma unroll
  for (int j = 0; j < 4; ++j) {
    gload_lds16(aptr[j], &As[0][(wid * 32 + j * 8) * 64]);
    gload_lds16(bptr[j], &Bs[0][(wid * 32 + j * 8) * 64]);
    aptr[j] += 64; bptr[j] += 64;
  }
  __syncthreads();

  int cur = 0;
  for (int kt = 0; kt < 12; ++kt) {
    if (kt < 11) {
#pragma unroll
      for (int j = 0; j < 4; ++j) {
        gload_lds16(aptr[j], &As[cur ^ 1][(wid * 32 + j * 8) * 64]);
        gload_lds16(bptr[j], &Bs[cur ^ 1][(wid * 32 + j * 8) * 64]);
        aptr[j] += 64; bptr[j] += 64;
      }
    }
    bf16x8 af[2][4], bfr[2][4];
#pragma unroll
    for (int kf = 0; kf < 2; ++kf)
#pragma unroll
      for (int mf = 0; mf < 4; ++mf)
        af[kf][mf] = *(const bf16x8*)&As[cur][(wm * 64 + mf * 16 + (lane & 15)) * 64 + ((kf * 32 + (lane >> 4) * 8) ^ axor)];
#pragma unroll
    for (int kf = 0; kf < 2; ++kf)
#pragma unroll
      for (int nf = 0; nf < 4; ++nf)
        bfr[kf][nf] = *(const bf16x8*)&Bs[cur][(wn * 64 + nf * 16 + (lane & 15)) * 64 + ((kf * 32 + (lane >> 4) * 8) ^ axor)];
#pragma unroll
    for (int mf = 0; mf < 4; ++mf)
#pragma unroll
      for (int nf = 0; nf < 4; ++nf) {
        acc[mf][nf] = __builtin_amdgcn_mfma_f32_16x16x32_bf16(af[0][mf], bfr[0][nf], acc[mf][nf], 0, 0, 0);
        acc[mf][nf] = __builtin_amdgcn_mfma_f32_16x16x32_bf16(af[1][mf], bfr[1][nf], acc[mf][nf], 0, 0, 0);
      }
    __syncthreads();
    cur ^= 1;
  }

  float* Hb = Ht + (size_t)b * 640 * DD;
#pragma unroll
  for (int mf = 0; mf < 4; ++mf)
#pragma unroll
    for (int nf = 0; nf < 4; ++nf)
#pragma unroll
      for (int r = 0; r < 4; ++r) {
        int row = m0 + wm * 64 + mf * 16 + (lane >> 4) * 4 + r;
        int col = n0 + wn * 64 + nf * 16 + (lane & 15);
        Hb[(size_t)row * DD + col] = acc[mf][nf][r];
      }
}

// ---------------- gemm_h: 128x96 tiles; Hcore = Qpad @ Wcomb^T + fused score ----------------
__global__ __launch_bounds__(256, 2)
void gemm_h(const u16* __restrict__ Q, const float* __restrict__ Ht,
            const int* __restrict__ ids, const u16* __restrict__ Wcomb,
            const float* __restrict__ bf1x, const float* __restrict__ w2,
            const float* __restrict__ mask, float* __restrict__ out) {
  int flat = blockIdx.x;   // 1504 = 8*188
  int lid = (flat & 7) * 188 + (flat >> 3);
  int n = lid % 8;
  int m = (lid / 8) % 47;
  int b = lid / 376;

  const int m0 = m * 128;
  const int n0 = n * 96;
  const int tid = threadIdx.x;
  const int lane = tid & 63;
  const int wid = tid >> 6;
  const int wm = wid >> 1, wn = wid & 1;   // wave-tile 64x48

  __shared__ u16 As[2][128 * 64];
  __shared__ u16 Bs[2][96 * 64];
  __shared__ int sids[100];
  __shared__ float pacc[4];
  if (tid < 100) sids[tid] = ids[b * 100 + tid];
  if (tid < 4) pacc[tid] = 0.f;
  __syncthreads();

  const u16* Abase = Q + (size_t)b * MPAD * DD;
  const u16* Bbase = Wcomb + (size_t)b * DD * DD;

  f32x4 acc[4][3] = {};

  const int lrow = lane >> 3;
  const int lcol_s = (((lane & 7) ^ (lrow & 7)) * 8);
  const int axor = (lane & 7) << 3;

  const u16* aptr[4];
  const u16* bptr[3];
#pragma unroll
  for (int j = 0; j < 4; ++j)
    aptr[j] = Abase + (size_t)(m0 + wid * 32 + j * 8 + lrow) * DD + lcol_s;
#pragma unroll
  for (int j = 0; j < 3; ++j)
    bptr[j] = Bbase + (size_t)(n0 + wid * 24 + j * 8 + lrow) * DD + lcol_s;

#pragma unroll
  for (int j = 0; j < 4; ++j) {
    gload_lds16(aptr[j], &As[0][(wid * 32 + j * 8) * 64]);
    aptr[j] += 64;
  }
#pragma unroll
  for (int j = 0; j < 3; ++j) {
    gload_lds16(bptr[j], &Bs[0][(wid * 24 + j * 8) * 64]);
    bptr[j] += 64;
  }
  __syncthreads();

  int cur = 0;
  for (int kt = 0; kt < 12; ++kt) {
    if (kt < 11) {
#pragma unroll
      for (int j = 0; j < 4; ++j) {
        gload_lds16(aptr[j], &As[cur ^ 1][(wid * 32 + j * 8) * 64]);
        aptr[j] += 64;
      }
#pragma unroll
      for (int j = 0; j < 3; ++j) {
        gload_lds16(bptr[j], &Bs[cur ^ 1][(wid * 24 + j * 8) * 64]);
        bptr[j] += 64;
      }
    }
    bf16x8 af[2][4], bfr[2][3];
#pragma unroll
    for (int kf = 0; kf < 2; ++kf)
#pragma unroll
      for (int mf = 0; mf < 4; ++mf)
        af[kf][mf] = *(const bf16x8*)&As[cur][(wm * 64 + mf * 16 + (lane & 15)) * 64 + ((kf * 32 + (lane >> 4) * 8) ^ axor)];
#pragma unroll
    for (int kf = 0; kf < 2; ++kf)
#pragma unroll
      for (int nf = 0; nf < 3; ++nf)
        bfr[kf][nf] = *(const bf16x8*)&Bs[cur][(wn * 48 + nf * 16 + (lane & 15)) * 64 + ((kf * 32 + (lane >> 4) * 8) ^ axor)];
#pragma unroll
    for (int mf = 0; mf < 4; ++mf)
#pragma unroll
      for (int nf = 0; nf < 3; ++nf) {
        acc[mf][nf] = __builtin_amdgcn_mfma_f32_16x16x32_bf16(af[0][mf], bfr[0][nf], acc[mf][nf], 0, 0, 0);
        acc[mf][nf] = __builtin_amdgcn_mfma_f32_16x16x32_bf16(af[1][mf], bfr[1][nf], acc[mf][nf], 0, 0, 0);
      }
    __syncthreads();
    cur ^= 1;
  }

  // fused score epilogue: H = Hcore + Ht[gather] + bf1x[b]
  float b1v[3], w2v[3];
  int cbase = n0 + wn * 48 + (lane & 15);
#pragma unroll
  for (int nf = 0; nf < 3; ++nf) {
    b1v[nf] = bf1x[b * DD + cbase + nf * 16];
    w2v[nf] = w2[cbase + nf * 16];
  }
  const float* Hb = Ht + (size_t)b * 640 * DD;
  const int pfirst = m0 / 60;
#pragma unroll
  for (int mf = 0; mf < 4; ++mf)
#pragma unroll
    for (int r = 0; r < 4; ++r) {
      int row = m0 + wm * 64 + mf * 16 + (lane >> 4) * 4 + r;
      if (row < 6000) {
        int p = (unsigned)row / 60u;
        int tok = row - p * 60;
        const float* htrow = Hb + (size_t)(sids[p] * 60 + tok) * DD + cbase;
        float s = 0.f;
#pragma unroll
        for (int nf = 0; nf < 3; ++nf)
          s += fmaxf(acc[mf][nf][r] + htrow[nf * 16] + b1v[nf], 0.f) * w2v[nf];
        s += __shfl_xor(s, 1);
        s += __shfl_xor(s, 2);
        s += __shfl_xor(s, 4);
        s += __shfl_xor(s, 8);
        if ((lane & 15) == 0) {
          float mk = mask[((size_t)b * 100 + p) * 60 + tok];
          atomicAdd(&pacc[p - pfirst], mk * s);
        }
      }
    }
  __syncthreads();
  int plast = (m0 + 127 < 6000 ? m0 + 127 : 5999) / 60;
  if (tid <= plast - pfirst)
    atomicAdd(out + b * 100 + pfirst + tid, pacc[tid]);
}

// ---------------- launch ----------------
extern "C" void kernel_launch(void* const* d_in, const int* in_sizes, int n_in,
                              void* d_out, int out_size, void* d_ws, size_t ws_size,
                              hipStream_t stream) {
  const float* answer = (const float*)d_in[0];
  const float* qps    = (const float*)d_in[1];
  const float* mask   = (const float*)d_in[2];
  const int*   tids   = (const int*)d_in[3];
  const float* Wp     = (const float*)d_in[4];
  const float* bp     = (const float*)d_in[5];
  const float* Wt     = (const float*)d_in[6];
  const float* bt     = (const float*)d_in[7];
  const float* Wf1    = (const float*)d_in[8];
  const float* bf1    = (const float*)d_in[9];
  const float* Wf2    = (const float*)d_in[10];
  const float* bf2    = (const float*)d_in[11];
  float* out = (float*)d_out;

  char* ws = (char*)d_ws;
  // region layout (bytes); total ~102 MB
  u16* Qpad  = (u16*)(ws + 0);            // 36,962,304
  u16* ts    = (u16*)(ws + 36962304);     // 36,962,304
  u16* tmax  = (u16*)(ws + 73924608);     //  3,686,400
  float* Ht  = (float*)(ws + 77611008);   //  7,864,320
  u16* Wtb   = (u16*)(ws + 85475328);     //  4,718,592
  u16* WpbT  = (u16*)(ws + 90193920);     //  4,718,592
  u16* Wcomb = (u16*)(ws + 94912512);     //  4,718,592
  u16* Wf1b  = (u16*)(ws + 99631104);     //  2,359,296
  float* cp  = (float*)(ws + 101990400);  //     12,288
  float* ct  = (float*)(ws + 102002688);  //     12,288
  float* bf1x= (float*)(ws + 102014976);  //     12,288

  prep_all<<<12866, 256, 0, stream>>>(qps, (uint4*)Qpad, answer, Wp, Wt, Wtb, WpbT,
                                      Wf1, (uint4*)Wf1b, bp, bt, cp, ct,
                                      mask, bf2, out);

  mid_kernel<<<2040, 256, 0, stream>>>(Qpad, Wtb, ct, ts, Wf1b, WpbT, Wcomb,
                                       Wf1, cp, bf1, bf1x);

  table_max_kernel<<<720, 256, 0, stream>>>(ts, tids, tmax);

  gemm_t<<<120, 256, 0, stream>>>(tmax, Wf1b, Ht);

  gemm_h<<<1504, 256, 0, stream>>>(Qpad, Ht, tids, Wcomb, bf1x, Wf2, mask, out);
}

// Round 13
// 188.570 us; speedup vs baseline: 1.6629x; 1.0367x over previous
//
#include <hip/hip_runtime.h>
#include <hip/hip_bf16.h>

// FusionRetrModel: B=4, NL=2 (only l=1 used), P=100, TOK=60, T=6000, D=768.
// R13 pipeline (single-buffer occupancy experiment):
//   prep_all: Qpad bf16; Wtb; WpbT; Wf1 cast; cp/ct GEMV; out init.
//   mid (SINGLE-buffer LDS, 32KB -> up to 5 blocks/CU; wc first):
//     [0,144)     gemm_wc   [144,1272) gemm_ts   [1272,2040) prep2
//   tmax:   per-table max over passages
//   gemm_t: 64x128 tiles, 240 blocks, single-buffer (was 120 x 128^2)
//   gemm_h: UNCHANGED dbuf 128x96 (control for the A/B vs mid)
// GEMMs: BK=64, T2 swizzle (src-side), 0 bank conflicts.
// Workspace: ~102 MB.

typedef unsigned short u16;
typedef unsigned int u32;
typedef __attribute__((ext_vector_type(8))) short bf16x8;
typedef __attribute__((ext_vector_type(4))) float f32x4;

#define NUM_TABLES 10
#define MPAD 6016
#define DD 768

__device__ __forceinline__ u16 f2bf(float f) {
  u32 u = __builtin_bit_cast(u32, f);
  u32 r = u + 0x7FFFu + ((u >> 16) & 1u);
  return (u16)(r >> 16);
}
__device__ __forceinline__ float bf2f(u16 h) {
  u32 u = ((u32)h) << 16;
  return __builtin_bit_cast(float, u);
}
__device__ __forceinline__ u32 pack_bf2(float lo, float hi) {
  return (u32)f2bf(lo) | ((u32)f2bf(hi) << 16);
}

__device__ __forceinline__ void gload_lds16(const u16* g, u16* l) {
  __builtin_amdgcn_global_load_lds(
      (const __attribute__((address_space(1))) void*)g,
      (__attribute__((address_space(3))) void*)l, 16, 0, 0);
}

// ---------------- fused prep (one dispatch) ----------------
__global__ void prep_all(const float* __restrict__ qps, uint4* __restrict__ qpad,
                         const float* __restrict__ Ans, const float* __restrict__ Wp,
                         const float* __restrict__ Wt, u16* __restrict__ Wtb,
                         u16* __restrict__ WpbT,
                         const float* __restrict__ Wf1, uint4* __restrict__ Wf1b,
                         const float* __restrict__ bp, const float* __restrict__ bt,
                         float* __restrict__ cp, float* __restrict__ ct,
                         const float* __restrict__ mask, const float* __restrict__ bf2,
                         float* __restrict__ out) {
  int blk = blockIdx.x;
  int tid = threadIdx.x;
  if (blk < 9024) {
    // ---- Qpad: cast l=1 slice to bf16, pad rows [6000,6016) ----
    size_t c = (size_t)blk * 256 + tid;
    const int per_b = MPAD * (DD / 8);
    int b = (int)(c / per_b);
    int rr = (int)(c % per_b);
    int r = rr / (DD / 8);
    int kc = rr % (DD / 8);
    uint4 o;
    if (r < 6000) {
      const float* src = qps + (((size_t)(b * 2 + 1)) * 6000 + r) * DD + kc * 8;
      float4 f0 = *(const float4*)src;
      float4 f1 = *(const float4*)(src + 4);
      o.x = pack_bf2(f0.x, f0.y);
      o.y = pack_bf2(f0.z, f0.w);
      o.z = pack_bf2(f1.x, f1.y);
      o.w = pack_bf2(f1.z, f1.w);
    } else {
      o = make_uint4(0, 0, 0, 0);
    }
    qpad[c] = o;
  } else if (blk < 10176) {
    // ---- Wtb[b][d][k] = Wt[d][768+k] + A[b][k]*Wt[d][1536+k] ----
    size_t c = (size_t)(blk - 9024) * 256 + tid;
    const int per_b = DD * (DD / 8);
    int b = (int)(c / per_b);
    int rr = (int)(c % per_b);
    int d = rr / (DD / 8);
    int k8 = (rr % (DD / 8)) * 8;
    const float* a = Ans + ((size_t)b * 2 + 1) * DD + k8;
    const float* w2r = Wt + (size_t)d * 2304 + 768 + k8;
    const float* w3r = Wt + (size_t)d * 2304 + 1536 + k8;
    float4 a0 = *(const float4*)a, a1 = *(const float4*)(a + 4);
    float4 t20 = *(const float4*)w2r, t21 = *(const float4*)(w2r + 4);
    float4 t30 = *(const float4*)w3r, t31 = *(const float4*)(w3r + 4);
    uint4 o;
    o.x = pack_bf2(t20.x + a0.x * t30.x, t20.y + a0.y * t30.y);
    o.y = pack_bf2(t20.z + a0.z * t30.z, t20.w + a0.w * t30.w);
    o.z = pack_bf2(t21.x + a1.x * t31.x, t21.y + a1.y * t31.y);
    o.w = pack_bf2(t21.z + a1.z * t31.z, t21.w + a1.w * t31.w);
    *(uint4*)(Wtb + ((size_t)b * DD + d) * DD + k8) = o;
  } else if (blk < 10752) {
    // ---- WpbT[b][k][d] = Wp[d][768+k] + A[b][k]*Wp[d][1536+k] (LDS transpose) ----
    int tb = blk - 10176;
    int b = tb / 144;
    int tt = tb % 144;
    int k0 = (tt / 12) * 64, d0 = (tt % 12) * 64;
    __shared__ u16 tile[64][72];
    int kc = tid & 63;
    int r0 = tid >> 6;
    float av = Ans[((size_t)b * 2 + 1) * DD + k0 + kc];
#pragma unroll
    for (int it = 0; it < 16; ++it) {
      int dr = it * 4 + r0;
      const float* wrow = Wp + (size_t)(d0 + dr) * 2304;
      float v = wrow[768 + k0 + kc] + av * wrow[1536 + k0 + kc];
      tile[kc][dr] = f2bf(v);
    }
    __syncthreads();
#pragma unroll
    for (int it = 0; it < 2; ++it) {
      int kk = it * 32 + (tid >> 3);
      int dd = (tid & 7) * 8;
      *(uint4*)(WpbT + ((size_t)b * DD + k0 + kk) * DD + d0 + dd) =
          *(const uint4*)&tile[kk][dd];
    }
  } else if (blk < 11328) {
    // ---- Wf1 cast ----
    size_t c = (size_t)(blk - 10752) * 256 + tid;
    const float* src = Wf1 + c * 8;
    float4 f0 = *(const float4*)src;
    float4 f1 = *(const float4*)(src + 4);
    uint4 o;
    o.x = pack_bf2(f0.x, f0.y);
    o.y = pack_bf2(f0.z, f0.w);
    o.z = pack_bf2(f1.x, f1.y);
    o.w = pack_bf2(f1.z, f1.w);
    Wf1b[c] = o;
  } else if (blk < 12864) {
    // ---- cp/ct parallel: one block per (matrix, d) ----
    int e = blk - 11328;
    int isT = e >= 768;
    int d = e - (isT ? 768 : 0);
    const float* wrow = (isT ? Wt : Wp) + (size_t)d * 2304;
    float a0 = 0.f, a1 = 0.f, a2 = 0.f, a3 = 0.f;
    for (int k = tid; k < DD; k += 256) {
      float w = wrow[k];
      a0 += w * Ans[1 * DD + k];
      a1 += w * Ans[3 * DD + k];
      a2 += w * Ans[5 * DD + k];
      a3 += w * Ans[7 * DD + k];
    }
#pragma unroll
    for (int off = 32; off > 0; off >>= 1) {
      a0 += __shfl_down(a0, off);
      a1 += __shfl_down(a1, off);
      a2 += __shfl_down(a2, off);
      a3 += __shfl_down(a3, off);
    }
    __shared__ float red[4][4];
    int wid = tid >> 6;
    if ((tid & 63) == 0) {
      red[wid][0] = a0; red[wid][1] = a1; red[wid][2] = a2; red[wid][3] = a3;
    }
    __syncthreads();
    if (tid < 4) {
      float s = red[0][tid] + red[1][tid] + red[2][tid] + red[3][tid];
      float bias = (isT ? bt : bp)[d];
      (isT ? ct : cp)[tid * DD + d] = s + bias;
    }
  } else {
    // ---- out init = bf2 * msum ----
    int idx = (blk - 12864) * 256 + tid;
    if (idx >= 400) return;
    const float* m = mask + (size_t)idx * 60;
    float s = 0.f;
    for (int t = 0; t < 60; ++t) s += m[t];
    out[idx] = bf2[0] * s;
  }
}

// ---------------- mid: gemm_wc | gemm_ts | prep2 (single-buffer LDS) ----------------
__global__ __launch_bounds__(256, 3)
void mid_kernel(const u16* __restrict__ Q, const u16* __restrict__ Wtb,
                const float* __restrict__ ct, u16* __restrict__ ts,
                const u16* __restrict__ Wf1b, const u16* __restrict__ WpbT,
                u16* __restrict__ Wcomb, const float* __restrict__ Wf1,
                const float* __restrict__ cp, const float* __restrict__ bf1,
                float* __restrict__ bf1x) {
  __shared__ u16 As[128 * 64];
  __shared__ u16 Bs[128 * 64];
  __shared__ float red[4][4];
  int blk = blockIdx.x;
  int tid = threadIdx.x;

  if (blk >= 1272) {
    // ---- prep2: bf1x[b][c] = bf1[c] + Wf1_lo[c,:].cp[b,:] ----
    int c = blk - 1272;
    const float* wrow = Wf1 + (size_t)c * 1536;
    float a0 = 0.f, a1 = 0.f, a2 = 0.f, a3 = 0.f;
    for (int d = tid; d < DD; d += 256) {
      float w = wrow[d];
      a0 += w * cp[0 * DD + d];
      a1 += w * cp[1 * DD + d];
      a2 += w * cp[2 * DD + d];
      a3 += w * cp[3 * DD + d];
    }
#pragma unroll
    for (int off = 32; off > 0; off >>= 1) {
      a0 += __shfl_down(a0, off);
      a1 += __shfl_down(a1, off);
      a2 += __shfl_down(a2, off);
      a3 += __shfl_down(a3, off);
    }
    int wid = tid >> 6;
    if ((tid & 63) == 0) {
      red[wid][0] = a0; red[wid][1] = a1; red[wid][2] = a2; red[wid][3] = a3;
    }
    __syncthreads();
    if (tid < 4) {
      float s = red[0][tid] + red[1][tid] + red[2][tid] + red[3][tid];
      bf1x[tid * DD + c] = bf1[c] + s;
    }
    return;
  }

  const int lane = tid & 63;
  const int wid = tid >> 6;
  const int wm = wid >> 1, wn = wid & 1;
  const int lrow = lane >> 3;
  const int lcol_s = (((lane & 7) ^ (lrow & 7)) * 8);
  const int axor = (lane & 7) << 3;
  f32x4 acc[4][4] = {};

  if (blk >= 144) {
    // ---- gemm_ts: ts = Qpad @ Wtb^T + ct (single-buffer, 2 barriers/K-step) ----
    int g = blk - 144;
    int lid = (g & 7) * 141 + (g >> 3);
    int n = lid % 6;
    int m = (lid / 6) % 47;
    int b = lid / 282;
    const int m0 = m * 128;
    const int n0 = n * 128;

    const u16* Abase = Q + (size_t)b * MPAD * DD;
    const u16* Bbase = Wtb + (size_t)b * DD * DD;

    const u16* aptr[4];
    const u16* bptr[4];
#pragma unroll
    for (int j = 0; j < 4; ++j) {
      aptr[j] = Abase + (size_t)(m0 + wid * 32 + j * 8 + lrow) * DD + lcol_s;
      bptr[j] = Bbase + (size_t)(n0 + wid * 32 + j * 8 + lrow) * DD + lcol_s;
    }

    for (int kt = 0; kt < 12; ++kt) {
#pragma unroll
      for (int j = 0; j < 4; ++j) {
        gload_lds16(aptr[j], &As[(wid * 32 + j * 8) * 64]);
        gload_lds16(bptr[j], &Bs[(wid * 32 + j * 8) * 64]);
        aptr[j] += 64; bptr[j] += 64;
      }
      __syncthreads();
      bf16x8 af[2][4], bfr[2][4];
#pragma unroll
      for (int kf = 0; kf < 2; ++kf)
#pragma unroll
        for (int mf = 0; mf < 4; ++mf)
          af[kf][mf] = *(const bf16x8*)&As[(wm * 64 + mf * 16 + (lane & 15)) * 64 + ((kf * 32 + (lane >> 4) * 8) ^ axor)];
#pragma unroll
      for (int kf = 0; kf < 2; ++kf)
#pragma unroll
        for (int nf = 0; nf < 4; ++nf)
          bfr[kf][nf] = *(const bf16x8*)&Bs[(wn * 64 + nf * 16 + (lane & 15)) * 64 + ((kf * 32 + (lane >> 4) * 8) ^ axor)];
#pragma unroll
      for (int mf = 0; mf < 4; ++mf)
#pragma unroll
        for (int nf = 0; nf < 4; ++nf) {
          acc[mf][nf] = __builtin_amdgcn_mfma_f32_16x16x32_bf16(af[0][mf], bfr[0][nf], acc[mf][nf], 0, 0, 0);
          acc[mf][nf] = __builtin_amdgcn_mfma_f32_16x16x32_bf16(af[1][mf], bfr[1][nf], acc[mf][nf], 0, 0, 0);
        }
      __syncthreads();
    }

    u16* dst = ts + (size_t)b * MPAD * DD;
    const float* cv = ct + b * DD;
#pragma unroll
    for (int mf = 0; mf < 4; ++mf)
#pragma unroll
      for (int nf = 0; nf < 4; ++nf)
#pragma unroll
        for (int r = 0; r < 4; ++r) {
          int row = m0 + wm * 64 + mf * 16 + (lane >> 4) * 4 + r;
          int col = n0 + wn * 64 + nf * 16 + (lane & 15);
          dst[(size_t)row * DD + col] = f2bf(acc[mf][nf][r] + cv[col]);
        }
  } else {
    // ---- gemm_wc: Wcomb[b][c][k] = sum_d Wf1_lo[c][d] * WpbT[b][k][d] ----
    int f = blk;
    int lid = (f & 7) * 18 + (f >> 3);
    int n = lid % 6;
    int m = (lid / 6) % 6;
    int b = lid / 36;
    const int m0 = m * 128;
    const int n0 = n * 128;

    const u16* Bbase = WpbT + (size_t)b * DD * DD;
    const u16* aptr[4];
    const u16* bptr[4];
#pragma unroll
    for (int j = 0; j < 4; ++j) {
      aptr[j] = Wf1b + (size_t)(m0 + wid * 32 + j * 8 + lrow) * 1536 + lcol_s;
      bptr[j] = Bbase + (size_t)(n0 + wid * 32 + j * 8 + lrow) * DD + lcol_s;
    }

    for (int kt = 0; kt < 12; ++kt) {
#pragma unroll
      for (int j = 0; j < 4; ++j) {
        gload_lds16(aptr[j], &As[(wid * 32 + j * 8) * 64]);
        gload_lds16(bptr[j], &Bs[(wid * 32 + j * 8) * 64]);
        aptr[j] += 64; bptr[j] += 64;
      }
      __syncthreads();
      bf16x8 af[2][4], bfr[2][4];
#pragma unroll
      for (int kf = 0; kf < 2; ++kf)
#pragma unroll
        for (int mf = 0; mf < 4; ++mf)
          af[kf][mf] = *(const bf16x8*)&As[(wm * 64 + mf * 16 + (lane & 15)) * 64 + ((kf * 32 + (lane >> 4) * 8) ^ axor)];
#pragma unroll
      for (int kf = 0; kf < 2; ++kf)
#pragma unroll
        for (int nf = 0; nf < 4; ++nf)
          bfr[kf][nf] = *(const bf16x8*)&Bs[(wn * 64 + nf * 16 + (lane & 15)) * 64 + ((kf * 32 + (lane >> 4) * 8) ^ axor)];
#pragma unroll
      for (int mf = 0; mf < 4; ++mf)
#pragma unroll
        for (int nf = 0; nf < 4; ++nf) {
          acc[mf][nf] = __builtin_amdgcn_mfma_f32_16x16x32_bf16(af[0][mf], bfr[0][nf], acc[mf][nf], 0, 0, 0);
          acc[mf][nf] = __builtin_amdgcn_mfma_f32_16x16x32_bf16(af[1][mf], bfr[1][nf], acc[mf][nf], 0, 0, 0);
        }
      __syncthreads();
    }

    u16* Cb = Wcomb + (size_t)b * DD * DD;
#pragma unroll
    for (int mf = 0; mf < 4; ++mf)
#pragma unroll
      for (int nf = 0; nf < 4; ++nf)
#pragma unroll
        for (int r = 0; r < 4; ++r) {
          int row = m0 + wm * 64 + mf * 16 + (lane >> 4) * 4 + r;
          int col = n0 + wn * 64 + nf * 16 + (lane & 15);
          Cb[(size_t)row * DD + col] = f2bf(acc[mf][nf][r]);
        }
  }
}

// ---------------- table max ----------------
__global__ void table_max_kernel(const u16* __restrict__ ts, const int* __restrict__ ids,
                                 u16* __restrict__ tmax) {
  int bi = blockIdx.x;  // 720
  int b = bi / 180;
  int rem = bi % 180;
  int tok = rem / 3;
  int dc = rem % 3;
  int d = dc * 256 + threadIdx.x;
  __shared__ int sids[100];
  if (threadIdx.x < 100) sids[threadIdx.x] = ids[b * 100 + threadIdx.x];
  __syncthreads();
  float m[NUM_TABLES];
#pragma unroll
  for (int t = 0; t < NUM_TABLES; ++t) m[t] = -INFINITY;
  const u16* base = ts + ((size_t)b * MPAD + tok) * DD + d;
  for (int p = 0; p < 100; ++p) {
    float v = bf2f(base[(size_t)p * 60 * DD]);
    int id = sids[p];
#pragma unroll
    for (int t = 0; t < NUM_TABLES; ++t)
      if (id == t) m[t] = fmaxf(m[t], v);
  }
#pragma unroll
  for (int t = 0; t < NUM_TABLES; ++t)
    tmax[(((size_t)b * NUM_TABLES + t) * 60 + tok) * DD + d] = f2bf(m[t]);
}

// ---------------- gemm_t: 64x128 tiles, 240 blocks, single-buffer ----------------
__global__ __launch_bounds__(256, 3)
void gemm_t(const u16* __restrict__ tmax, const u16* __restrict__ Wf1b,
            float* __restrict__ Ht) {
  int flat = blockIdx.x;   // 240 = 8*30
  int lid = (flat & 7) * 30 + (flat >> 3);
  int n = lid % 6;
  int m = (lid / 6) % 10;
  int b = lid / 60;

  const int m0 = m * 64;
  const int n0 = n * 128;
  const int tid = threadIdx.x;
  const int lane = tid & 63;
  const int wid = tid >> 6;
  const int wm = wid >> 1, wn = wid & 1;   // wave-tile 32x64

  __shared__ u16 As[64 * 64];
  __shared__ u16 Bs[128 * 64];

  const u16* Abase = tmax + (size_t)b * 600 * DD;

  f32x4 acc[2][4] = {};

  const int lrow = lane >> 3;
  const int lcol_s = (((lane & 7) ^ (lrow & 7)) * 8);
  const int axor = (lane & 7) << 3;

  const u16* aptr[2];
  const u16* bptr[4];
#pragma unroll
  for (int j = 0; j < 2; ++j) {
    int row = m0 + wid * 16 + j * 8 + lrow;
    int rp = row < 600 ? row : 599;
    aptr[j] = Abase + (size_t)rp * DD + lcol_s;
  }
#pragma unroll
  for (int j = 0; j < 4; ++j)
    bptr[j] = Wf1b + (size_t)(n0 + wid * 32 + j * 8 + lrow) * 1536 + 768 + lcol_s;

  for (int kt = 0; kt < 12; ++kt) {
#pragma unroll
    for (int j = 0; j < 2; ++j) {
      gload_lds16(aptr[j], &As[(wid * 16 + j * 8) * 64]);
      aptr[j] += 64;
    }
#pragma unroll
    for (int j = 0; j < 4; ++j) {
      gload_lds16(bptr[j], &Bs[(wid * 32 + j * 8) * 64]);
      bptr[j] += 64;
    }
    __syncthreads();
    bf16x8 af[2][2], bfr[2][4];
#pragma unroll
    for (int kf = 0; kf < 2; ++kf)
#pragma unroll
      for (int mf = 0; mf < 2; ++mf)
        af[kf][mf] = *(const bf16x8*)&As[(wm * 32 + mf * 16 + (lane & 15)) * 64 + ((kf * 32 + (lane >> 4) * 8) ^ axor)];
#pragma unroll
    for (int kf = 0; kf < 2; ++kf)
#pragma unroll
      for (int nf = 0; nf < 4; ++nf)
        bfr[kf][nf] = *(const bf16x8*)&Bs[(wn * 64 + nf * 16 + (lane & 15)) * 64 + ((kf * 32 + (lane >> 4) * 8) ^ axor)];
#pragma unroll
    for (int mf = 0; mf < 2; ++mf)
#pragma unroll
      for (int nf = 0; nf < 4; ++nf) {
        acc[mf][nf] = __builtin_amdgcn_mfma_f32_16x16x32_bf16(af[0][mf], bfr[0][nf], acc[mf][nf], 0, 0, 0);
        acc[mf][nf] = __builtin_amdgcn_mfma_f32_16x16x32_bf16(af[1][mf], bfr[1][nf], acc[mf][nf], 0, 0, 0);
      }
    __syncthreads();
  }

  float* Hb = Ht + (size_t)b * 640 * DD;
#pragma unroll
  for (int mf = 0; mf < 2; ++mf)
#pragma unroll
    for (int nf = 0; nf < 4; ++nf)
#pragma unroll
      for (int r = 0; r < 4; ++r) {
        int row = m0 + wm * 32 + mf * 16 + (lane >> 4) * 4 + r;
        int col = n0 + wn * 64 + nf * 16 + (lane & 15);
        Hb[(size_t)row * DD + col] = acc[mf][nf][r];
      }
}

// ---------------- gemm_h: 128x96 tiles dbuf (unchanged control) ----------------
__global__ __launch_bounds__(256, 2)
void gemm_h(const u16* __restrict__ Q, const float* __restrict__ Ht,
            const int* __restrict__ ids, const u16* __restrict__ Wcomb,
            const float* __restrict__ bf1x, const float* __restrict__ w2,
            const float* __restrict__ mask, float* __restrict__ out) {
  int flat = blockIdx.x;   // 1504 = 8*188
  int lid = (flat & 7) * 188 + (flat >> 3);
  int n = lid % 8;
  int m = (lid / 8) % 47;
  int b = lid / 376;

  const int m0 = m * 128;
  const int n0 = n * 96;
  const int tid = threadIdx.x;
  const int lane = tid & 63;
  const int wid = tid >> 6;
  const int wm = wid >> 1, wn = wid & 1;   // wave-tile 64x48

  __shared__ u16 As[2][128 * 64];
  __shared__ u16 Bs[2][96 * 64];
  __shared__ int sids[100];
  __shared__ float pacc[4];
  if (tid < 100) sids[tid] = ids[b * 100 + tid];
  if (tid < 4) pacc[tid] = 0.f;
  __syncthreads();

  const u16* Abase = Q + (size_t)b * MPAD * DD;
  const u16* Bbase = Wcomb + (size_t)b * DD * DD;

  f32x4 acc[4][3] = {};

  const int lrow = lane >> 3;
  const int lcol_s = (((lane & 7) ^ (lrow & 7)) * 8);
  const int axor = (lane & 7) << 3;

  const u16* aptr[4];
  const u16* bptr[3];
#pragma unroll
  for (int j = 0; j < 4; ++j)
    aptr[j] = Abase + (size_t)(m0 + wid * 32 + j * 8 + lrow) * DD + lcol_s;
#pragma unroll
  for (int j = 0; j < 3; ++j)
    bptr[j] = Bbase + (size_t)(n0 + wid * 24 + j * 8 + lrow) * DD + lcol_s;

#pragma unroll
  for (int j = 0; j < 4; ++j) {
    gload_lds16(aptr[j], &As[0][(wid * 32 + j * 8) * 64]);
    aptr[j] += 64;
  }
#pragma unroll
  for (int j = 0; j < 3; ++j) {
    gload_lds16(bptr[j], &Bs[0][(wid * 24 + j * 8) * 64]);
    bptr[j] += 64;
  }
  __syncthreads();

  int cur = 0;
  for (int kt = 0; kt < 12; ++kt) {
    if (kt < 11) {
#pragma unroll
      for (int j = 0; j < 4; ++j) {
        gload_lds16(aptr[j], &As[cur ^ 1][(wid * 32 + j * 8) * 64]);
        aptr[j] += 64;
      }
#pragma unroll
      for (int j = 0; j < 3; ++j) {
        gload_lds16(bptr[j], &Bs[cur ^ 1][(wid * 24 + j * 8) * 64]);
        bptr[j] += 64;
      }
    }
    bf16x8 af[2][4], bfr[2][3];
#pragma unroll
    for (int kf = 0; kf < 2; ++kf)
#pragma unroll
      for (int mf = 0; mf < 4; ++mf)
        af[kf][mf] = *(const bf16x8*)&As[cur][(wm * 64 + mf * 16 + (lane & 15)) * 64 + ((kf * 32 + (lane >> 4) * 8) ^ axor)];
#pragma unroll
    for (int kf = 0; kf < 2; ++kf)
#pragma unroll
      for (int nf = 0; nf < 3; ++nf)
        bfr[kf][nf] = *(const bf16x8*)&Bs[cur][(wn * 48 + nf * 16 + (lane & 15)) * 64 + ((kf * 32 + (lane >> 4) * 8) ^ axor)];
#pragma unroll
    for (int mf = 0; mf < 4; ++mf)
#pragma unroll
      for (int nf = 0; nf < 3; ++nf) {
        acc[mf][nf] = __builtin_amdgcn_mfma_f32_16x16x32_bf16(af[0][mf], bfr[0][nf], acc[mf][nf], 0, 0, 0);
        acc[mf][nf] = __builtin_amdgcn_mfma_f32_16x16x32_bf16(af[1][mf], bfr[1][nf], acc[mf][nf], 0, 0, 0);
      }
    __syncthreads();
    cur ^= 1;
  }

  // fused score epilogue: H = Hcore + Ht[gather] + bf1x[b]
  float b1v[3], w2v[3];
  int cbase = n0 + wn * 48 + (lane & 15);
#pragma unroll
  for (int nf = 0; nf < 3; ++nf) {
    b1v[nf] = bf1x[b * DD + cbase + nf * 16];
    w2v[nf] = w2[cbase + nf * 16];
  }
  const float* Hb = Ht + (size_t)b * 640 * DD;
  const int pfirst = m0 / 60;
#pragma unroll
  for (int mf = 0; mf < 4; ++mf)
#pragma unroll
    for (int r = 0; r < 4; ++r) {
      int row = m0 + wm * 64 + mf * 16 + (lane >> 4) * 4 + r;
      if (row < 6000) {
        int p = (unsigned)row / 60u;
        int tok = row - p * 60;
        const float* htrow = Hb + (size_t)(sids[p] * 60 + tok) * DD + cbase;
        float s = 0.f;
#pragma unroll
        for (int nf = 0; nf < 3; ++nf)
          s += fmaxf(acc[mf][nf][r] + htrow[nf * 16] + b1v[nf], 0.f) * w2v[nf];
        s += __shfl_xor(s, 1);
        s += __shfl_xor(s, 2);
        s += __shfl_xor(s, 4);
        s += __shfl_xor(s, 8);
        if ((lane & 15) == 0) {
          float mk = mask[((size_t)b * 100 + p) * 60 + tok];
          atomicAdd(&pacc[p - pfirst], mk * s);
        }
      }
    }
  __syncthreads();
  int plast = (m0 + 127 < 6000 ? m0 + 127 : 5999) / 60;
  if (tid <= plast - pfirst)
    atomicAdd(out + b * 100 + pfirst + tid, pacc[tid]);
}

// ---------------- launch ----------------
extern "C" void kernel_launch(void* const* d_in, const int* in_sizes, int n_in,
                              void* d_out, int out_size, void* d_ws, size_t ws_size,
                              hipStream_t stream) {
  const float* answer = (const float*)d_in[0];
  const float* qps    = (const float*)d_in[1];
  const float* mask   = (const float*)d_in[2];
  const int*   tids   = (const int*)d_in[3];
  const float* Wp     = (const float*)d_in[4];
  const float* bp     = (const float*)d_in[5];
  const float* Wt     = (const float*)d_in[6];
  const float* bt     = (const float*)d_in[7];
  const float* Wf1    = (const float*)d_in[8];
  const float* bf1    = (const float*)d_in[9];
  const float* Wf2    = (const float*)d_in[10];
  const float* bf2    = (const float*)d_in[11];
  float* out = (float*)d_out;

  char* ws = (char*)d_ws;
  // region layout (bytes); total ~102 MB
  u16* Qpad  = (u16*)(ws + 0);            // 36,962,304
  u16* ts    = (u16*)(ws + 36962304);     // 36,962,304
  u16* tmax  = (u16*)(ws + 73924608);     //  3,686,400
  float* Ht  = (float*)(ws + 77611008);   //  7,864,320
  u16* Wtb   = (u16*)(ws + 85475328);     //  4,718,592
  u16* WpbT  = (u16*)(ws + 90193920);     //  4,718,592
  u16* Wcomb = (u16*)(ws + 94912512);     //  4,718,592
  u16* Wf1b  = (u16*)(ws + 99631104);     //  2,359,296
  float* cp  = (float*)(ws + 101990400);  //     12,288
  float* ct  = (float*)(ws + 102002688);  //     12,288
  float* bf1x= (float*)(ws + 102014976);  //     12,288

  prep_all<<<12866, 256, 0, stream>>>(qps, (uint4*)Qpad, answer, Wp, Wt, Wtb, WpbT,
                                      Wf1, (uint4*)Wf1b, bp, bt, cp, ct,
                                      mask, bf2, out);

  mid_kernel<<<2040, 256, 0, stream>>>(Qpad, Wtb, ct, ts, Wf1b, WpbT, Wcomb,
                                       Wf1, cp, bf1, bf1x);

  table_max_kernel<<<720, 256, 0, stream>>>(ts, tids, tmax);

  gemm_t<<<240, 256, 0, stream>>>(tmax, Wf1b, Ht);

  gemm_h<<<1504, 256, 0, stream>>>(Qpad, Ht, tids, Wcomb, bf1x, Wf2, mask, out);
}

// Round 14
// 170.009 us; speedup vs baseline: 1.8445x; 1.1092x over previous
//
#include <hip/hip_runtime.h>
#include <hip/hip_bf16.h>

// FusionRetrModel: B=4, NL=2 (only l=1 used), P=100, TOK=60, T=6000, D=768.
// R14 pipeline (all GEMMs single-buffer after R13's A/B win: 32KB LDS ->
// 3-5 blocks/CU cross-block overlap beats dbuf@2 blocks/CU at K=12 loops):
//   prep_all: Qpad bf16; Wtb; WpbT; Wf1 cast; cp/ct GEMV; out init.
//   mid: [0,144) gemm_wc | [144,1272) gemm_ts | [1272,2040) prep2
//   tmax:   per-table max over passages
//   gemm_t: 64x128 tiles, 240 blocks
//   gemm_h: 128x96 tiles, 1504 blocks, NOW single-buffer (28KB LDS)
// GEMMs: BK=64, T2 swizzle (src-side), 0 bank conflicts.
// Workspace: ~102 MB.

typedef unsigned short u16;
typedef unsigned int u32;
typedef __attribute__((ext_vector_type(8))) short bf16x8;
typedef __attribute__((ext_vector_type(4))) float f32x4;

#define NUM_TABLES 10
#define MPAD 6016
#define DD 768

__device__ __forceinline__ u16 f2bf(float f) {
  u32 u = __builtin_bit_cast(u32, f);
  u32 r = u + 0x7FFFu + ((u >> 16) & 1u);
  return (u16)(r >> 16);
}
__device__ __forceinline__ float bf2f(u16 h) {
  u32 u = ((u32)h) << 16;
  return __builtin_bit_cast(float, u);
}
__device__ __forceinline__ u32 pack_bf2(float lo, float hi) {
  return (u32)f2bf(lo) | ((u32)f2bf(hi) << 16);
}

__device__ __forceinline__ void gload_lds16(const u16* g, u16* l) {
  __builtin_amdgcn_global_load_lds(
      (const __attribute__((address_space(1))) void*)g,
      (__attribute__((address_space(3))) void*)l, 16, 0, 0);
}

// ---------------- fused prep (one dispatch) ----------------
__global__ void prep_all(const float* __restrict__ qps, uint4* __restrict__ qpad,
                         const float* __restrict__ Ans, const float* __restrict__ Wp,
                         const float* __restrict__ Wt, u16* __restrict__ Wtb,
                         u16* __restrict__ WpbT,
                         const float* __restrict__ Wf1, uint4* __restrict__ Wf1b,
                         const float* __restrict__ bp, const float* __restrict__ bt,
                         float* __restrict__ cp, float* __restrict__ ct,
                         const float* __restrict__ mask, const float* __restrict__ bf2,
                         float* __restrict__ out) {
  int blk = blockIdx.x;
  int tid = threadIdx.x;
  if (blk < 9024) {
    // ---- Qpad: cast l=1 slice to bf16, pad rows [6000,6016) ----
    size_t c = (size_t)blk * 256 + tid;
    const int per_b = MPAD * (DD / 8);
    int b = (int)(c / per_b);
    int rr = (int)(c % per_b);
    int r = rr / (DD / 8);
    int kc = rr % (DD / 8);
    uint4 o;
    if (r < 6000) {
      const float* src = qps + (((size_t)(b * 2 + 1)) * 6000 + r) * DD + kc * 8;
      float4 f0 = *(const float4*)src;
      float4 f1 = *(const float4*)(src + 4);
      o.x = pack_bf2(f0.x, f0.y);
      o.y = pack_bf2(f0.z, f0.w);
      o.z = pack_bf2(f1.x, f1.y);
      o.w = pack_bf2(f1.z, f1.w);
    } else {
      o = make_uint4(0, 0, 0, 0);
    }
    qpad[c] = o;
  } else if (blk < 10176) {
    // ---- Wtb[b][d][k] = Wt[d][768+k] + A[b][k]*Wt[d][1536+k] ----
    size_t c = (size_t)(blk - 9024) * 256 + tid;
    const int per_b = DD * (DD / 8);
    int b = (int)(c / per_b);
    int rr = (int)(c % per_b);
    int d = rr / (DD / 8);
    int k8 = (rr % (DD / 8)) * 8;
    const float* a = Ans + ((size_t)b * 2 + 1) * DD + k8;
    const float* w2r = Wt + (size_t)d * 2304 + 768 + k8;
    const float* w3r = Wt + (size_t)d * 2304 + 1536 + k8;
    float4 a0 = *(const float4*)a, a1 = *(const float4*)(a + 4);
    float4 t20 = *(const float4*)w2r, t21 = *(const float4*)(w2r + 4);
    float4 t30 = *(const float4*)w3r, t31 = *(const float4*)(w3r + 4);
    uint4 o;
    o.x = pack_bf2(t20.x + a0.x * t30.x, t20.y + a0.y * t30.y);
    o.y = pack_bf2(t20.z + a0.z * t30.z, t20.w + a0.w * t30.w);
    o.z = pack_bf2(t21.x + a1.x * t31.x, t21.y + a1.y * t31.y);
    o.w = pack_bf2(t21.z + a1.z * t31.z, t21.w + a1.w * t31.w);
    *(uint4*)(Wtb + ((size_t)b * DD + d) * DD + k8) = o;
  } else if (blk < 10752) {
    // ---- WpbT[b][k][d] = Wp[d][768+k] + A[b][k]*Wp[d][1536+k] (LDS transpose) ----
    int tb = blk - 10176;
    int b = tb / 144;
    int tt = tb % 144;
    int k0 = (tt / 12) * 64, d0 = (tt % 12) * 64;
    __shared__ u16 tile[64][72];
    int kc = tid & 63;
    int r0 = tid >> 6;
    float av = Ans[((size_t)b * 2 + 1) * DD + k0 + kc];
#pragma unroll
    for (int it = 0; it < 16; ++it) {
      int dr = it * 4 + r0;
      const float* wrow = Wp + (size_t)(d0 + dr) * 2304;
      float v = wrow[768 + k0 + kc] + av * wrow[1536 + k0 + kc];
      tile[kc][dr] = f2bf(v);
    }
    __syncthreads();
#pragma unroll
    for (int it = 0; it < 2; ++it) {
      int kk = it * 32 + (tid >> 3);
      int dd = (tid & 7) * 8;
      *(uint4*)(WpbT + ((size_t)b * DD + k0 + kk) * DD + d0 + dd) =
          *(const uint4*)&tile[kk][dd];
    }
  } else if (blk < 11328) {
    // ---- Wf1 cast ----
    size_t c = (size_t)(blk - 10752) * 256 + tid;
    const float* src = Wf1 + c * 8;
    float4 f0 = *(const float4*)src;
    float4 f1 = *(const float4*)(src + 4);
    uint4 o;
    o.x = pack_bf2(f0.x, f0.y);
    o.y = pack_bf2(f0.z, f0.w);
    o.z = pack_bf2(f1.x, f1.y);
    o.w = pack_bf2(f1.z, f1.w);
    Wf1b[c] = o;
  } else if (blk < 12864) {
    // ---- cp/ct parallel: one block per (matrix, d) ----
    int e = blk - 11328;
    int isT = e >= 768;
    int d = e - (isT ? 768 : 0);
    const float* wrow = (isT ? Wt : Wp) + (size_t)d * 2304;
    float a0 = 0.f, a1 = 0.f, a2 = 0.f, a3 = 0.f;
    for (int k = tid; k < DD; k += 256) {
      float w = wrow[k];
      a0 += w * Ans[1 * DD + k];
      a1 += w * Ans[3 * DD + k];
      a2 += w * Ans[5 * DD + k];
      a3 += w * Ans[7 * DD + k];
    }
#pragma unroll
    for (int off = 32; off > 0; off >>= 1) {
      a0 += __shfl_down(a0, off);
      a1 += __shfl_down(a1, off);
      a2 += __shfl_down(a2, off);
      a3 += __shfl_down(a3, off);
    }
    __shared__ float red[4][4];
    int wid = tid >> 6;
    if ((tid & 63) == 0) {
      red[wid][0] = a0; red[wid][1] = a1; red[wid][2] = a2; red[wid][3] = a3;
    }
    __syncthreads();
    if (tid < 4) {
      float s = red[0][tid] + red[1][tid] + red[2][tid] + red[3][tid];
      float bias = (isT ? bt : bp)[d];
      (isT ? ct : cp)[tid * DD + d] = s + bias;
    }
  } else {
    // ---- out init = bf2 * msum ----
    int idx = (blk - 12864) * 256 + tid;
    if (idx >= 400) return;
    const float* m = mask + (size_t)idx * 60;
    float s = 0.f;
    for (int t = 0; t < 60; ++t) s += m[t];
    out[idx] = bf2[0] * s;
  }
}

// ---------------- mid: gemm_wc | gemm_ts | prep2 (single-buffer LDS) ----------------
__global__ __launch_bounds__(256, 3)
void mid_kernel(const u16* __restrict__ Q, const u16* __restrict__ Wtb,
                const float* __restrict__ ct, u16* __restrict__ ts,
                const u16* __restrict__ Wf1b, const u16* __restrict__ WpbT,
                u16* __restrict__ Wcomb, const float* __restrict__ Wf1,
                const float* __restrict__ cp, const float* __restrict__ bf1,
                float* __restrict__ bf1x) {
  __shared__ u16 As[128 * 64];
  __shared__ u16 Bs[128 * 64];
  __shared__ float red[4][4];
  int blk = blockIdx.x;
  int tid = threadIdx.x;

  if (blk >= 1272) {
    // ---- prep2: bf1x[b][c] = bf1[c] + Wf1_lo[c,:].cp[b,:] ----
    int c = blk - 1272;
    const float* wrow = Wf1 + (size_t)c * 1536;
    float a0 = 0.f, a1 = 0.f, a2 = 0.f, a3 = 0.f;
    for (int d = tid; d < DD; d += 256) {
      float w = wrow[d];
      a0 += w * cp[0 * DD + d];
      a1 += w * cp[1 * DD + d];
      a2 += w * cp[2 * DD + d];
      a3 += w * cp[3 * DD + d];
    }
#pragma unroll
    for (int off = 32; off > 0; off >>= 1) {
      a0 += __shfl_down(a0, off);
      a1 += __shfl_down(a1, off);
      a2 += __shfl_down(a2, off);
      a3 += __shfl_down(a3, off);
    }
    int wid = tid >> 6;
    if ((tid & 63) == 0) {
      red[wid][0] = a0; red[wid][1] = a1; red[wid][2] = a2; red[wid][3] = a3;
    }
    __syncthreads();
    if (tid < 4) {
      float s = red[0][tid] + red[1][tid] + red[2][tid] + red[3][tid];
      bf1x[tid * DD + c] = bf1[c] + s;
    }
    return;
  }

  const int lane = tid & 63;
  const int wid = tid >> 6;
  const int wm = wid >> 1, wn = wid & 1;
  const int lrow = lane >> 3;
  const int lcol_s = (((lane & 7) ^ (lrow & 7)) * 8);
  const int axor = (lane & 7) << 3;
  f32x4 acc[4][4] = {};

  if (blk >= 144) {
    // ---- gemm_ts: ts = Qpad @ Wtb^T + ct ----
    int g = blk - 144;
    int lid = (g & 7) * 141 + (g >> 3);
    int n = lid % 6;
    int m = (lid / 6) % 47;
    int b = lid / 282;
    const int m0 = m * 128;
    const int n0 = n * 128;

    const u16* Abase = Q + (size_t)b * MPAD * DD;
    const u16* Bbase = Wtb + (size_t)b * DD * DD;

    const u16* aptr[4];
    const u16* bptr[4];
#pragma unroll
    for (int j = 0; j < 4; ++j) {
      aptr[j] = Abase + (size_t)(m0 + wid * 32 + j * 8 + lrow) * DD + lcol_s;
      bptr[j] = Bbase + (size_t)(n0 + wid * 32 + j * 8 + lrow) * DD + lcol_s;
    }

    for (int kt = 0; kt < 12; ++kt) {
#pragma unroll
      for (int j = 0; j < 4; ++j) {
        gload_lds16(aptr[j], &As[(wid * 32 + j * 8) * 64]);
        gload_lds16(bptr[j], &Bs[(wid * 32 + j * 8) * 64]);
        aptr[j] += 64; bptr[j] += 64;
      }
      __syncthreads();
      bf16x8 af[2][4], bfr[2][4];
#pragma unroll
      for (int kf = 0; kf < 2; ++kf)
#pragma unroll
        for (int mf = 0; mf < 4; ++mf)
          af[kf][mf] = *(const bf16x8*)&As[(wm * 64 + mf * 16 + (lane & 15)) * 64 + ((kf * 32 + (lane >> 4) * 8) ^ axor)];
#pragma unroll
      for (int kf = 0; kf < 2; ++kf)
#pragma unroll
        for (int nf = 0; nf < 4; ++nf)
          bfr[kf][nf] = *(const bf16x8*)&Bs[(wn * 64 + nf * 16 + (lane & 15)) * 64 + ((kf * 32 + (lane >> 4) * 8) ^ axor)];
#pragma unroll
      for (int mf = 0; mf < 4; ++mf)
#pragma unroll
        for (int nf = 0; nf < 4; ++nf) {
          acc[mf][nf] = __builtin_amdgcn_mfma_f32_16x16x32_bf16(af[0][mf], bfr[0][nf], acc[mf][nf], 0, 0, 0);
          acc[mf][nf] = __builtin_amdgcn_mfma_f32_16x16x32_bf16(af[1][mf], bfr[1][nf], acc[mf][nf], 0, 0, 0);
        }
      __syncthreads();
    }

    u16* dst = ts + (size_t)b * MPAD * DD;
    const float* cv = ct + b * DD;
#pragma unroll
    for (int mf = 0; mf < 4; ++mf)
#pragma unroll
      for (int nf = 0; nf < 4; ++nf)
#pragma unroll
        for (int r = 0; r < 4; ++r) {
          int row = m0 + wm * 64 + mf * 16 + (lane >> 4) * 4 + r;
          int col = n0 + wn * 64 + nf * 16 + (lane & 15);
          dst[(size_t)row * DD + col] = f2bf(acc[mf][nf][r] + cv[col]);
        }
  } else {
    // ---- gemm_wc: Wcomb[b][c][k] = sum_d Wf1_lo[c][d] * WpbT[b][k][d] ----
    int f = blk;
    int lid = (f & 7) * 18 + (f >> 3);
    int n = lid % 6;
    int m = (lid / 6) % 6;
    int b = lid / 36;
    const int m0 = m * 128;
    const int n0 = n * 128;

    const u16* Bbase = WpbT + (size_t)b * DD * DD;
    const u16* aptr[4];
    const u16* bptr[4];
#pragma unroll
    for (int j = 0; j < 4; ++j) {
      aptr[j] = Wf1b + (size_t)(m0 + wid * 32 + j * 8 + lrow) * 1536 + lcol_s;
      bptr[j] = Bbase + (size_t)(n0 + wid * 32 + j * 8 + lrow) * DD + lcol_s;
    }

    for (int kt = 0; kt < 12; ++kt) {
#pragma unroll
      for (int j = 0; j < 4; ++j) {
        gload_lds16(aptr[j], &As[(wid * 32 + j * 8) * 64]);
        gload_lds16(bptr[j], &Bs[(wid * 32 + j * 8) * 64]);
        aptr[j] += 64; bptr[j] += 64;
      }
      __syncthreads();
      bf16x8 af[2][4], bfr[2][4];
#pragma unroll
      for (int kf = 0; kf < 2; ++kf)
#pragma unroll
        for (int mf = 0; mf < 4; ++mf)
          af[kf][mf] = *(const bf16x8*)&As[(wm * 64 + mf * 16 + (lane & 15)) * 64 + ((kf * 32 + (lane >> 4) * 8) ^ axor)];
#pragma unroll
      for (int kf = 0; kf < 2; ++kf)
#pragma unroll
        for (int nf = 0; nf < 4; ++nf)
          bfr[kf][nf] = *(const bf16x8*)&Bs[(wn * 64 + nf * 16 + (lane & 15)) * 64 + ((kf * 32 + (lane >> 4) * 8) ^ axor)];
#pragma unroll
      for (int mf = 0; mf < 4; ++mf)
#pragma unroll
        for (int nf = 0; nf < 4; ++nf) {
          acc[mf][nf] = __builtin_amdgcn_mfma_f32_16x16x32_bf16(af[0][mf], bfr[0][nf], acc[mf][nf], 0, 0, 0);
          acc[mf][nf] = __builtin_amdgcn_mfma_f32_16x16x32_bf16(af[1][mf], bfr[1][nf], acc[mf][nf], 0, 0, 0);
        }
      __syncthreads();
    }

    u16* Cb = Wcomb + (size_t)b * DD * DD;
#pragma unroll
    for (int mf = 0; mf < 4; ++mf)
#pragma unroll
      for (int nf = 0; nf < 4; ++nf)
#pragma unroll
        for (int r = 0; r < 4; ++r) {
          int row = m0 + wm * 64 + mf * 16 + (lane >> 4) * 4 + r;
          int col = n0 + wn * 64 + nf * 16 + (lane & 15);
          Cb[(size_t)row * DD + col] = f2bf(acc[mf][nf][r]);
        }
  }
}

// ---------------- table max ----------------
__global__ void table_max_kernel(const u16* __restrict__ ts, const int* __restrict__ ids,
                                 u16* __restrict__ tmax) {
  int bi = blockIdx.x;  // 720
  int b = bi / 180;
  int rem = bi % 180;
  int tok = rem / 3;
  int dc = rem % 3;
  int d = dc * 256 + threadIdx.x;
  __shared__ int sids[100];
  if (threadIdx.x < 100) sids[threadIdx.x] = ids[b * 100 + threadIdx.x];
  __syncthreads();
  float m[NUM_TABLES];
#pragma unroll
  for (int t = 0; t < NUM_TABLES; ++t) m[t] = -INFINITY;
  const u16* base = ts + ((size_t)b * MPAD + tok) * DD + d;
  for (int p = 0; p < 100; ++p) {
    float v = bf2f(base[(size_t)p * 60 * DD]);
    int id = sids[p];
#pragma unroll
    for (int t = 0; t < NUM_TABLES; ++t)
      if (id == t) m[t] = fmaxf(m[t], v);
  }
#pragma unroll
  for (int t = 0; t < NUM_TABLES; ++t)
    tmax[(((size_t)b * NUM_TABLES + t) * 60 + tok) * DD + d] = f2bf(m[t]);
}

// ---------------- gemm_t: 64x128 tiles, 240 blocks, single-buffer ----------------
__global__ __launch_bounds__(256, 3)
void gemm_t(const u16* __restrict__ tmax, const u16* __restrict__ Wf1b,
            float* __restrict__ Ht) {
  int flat = blockIdx.x;   // 240 = 8*30
  int lid = (flat & 7) * 30 + (flat >> 3);
  int n = lid % 6;
  int m = (lid / 6) % 10;
  int b = lid / 60;

  const int m0 = m * 64;
  const int n0 = n * 128;
  const int tid = threadIdx.x;
  const int lane = tid & 63;
  const int wid = tid >> 6;
  const int wm = wid >> 1, wn = wid & 1;   // wave-tile 32x64

  __shared__ u16 As[64 * 64];
  __shared__ u16 Bs[128 * 64];

  const u16* Abase = tmax + (size_t)b * 600 * DD;

  f32x4 acc[2][4] = {};

  const int lrow = lane >> 3;
  const int lcol_s = (((lane & 7) ^ (lrow & 7)) * 8);
  const int axor = (lane & 7) << 3;

  const u16* aptr[2];
  const u16* bptr[4];
#pragma unroll
  for (int j = 0; j < 2; ++j) {
    int row = m0 + wid * 16 + j * 8 + lrow;
    int rp = row < 600 ? row : 599;
    aptr[j] = Abase + (size_t)rp * DD + lcol_s;
  }
#pragma unroll
  for (int j = 0; j < 4; ++j)
    bptr[j] = Wf1b + (size_t)(n0 + wid * 32 + j * 8 + lrow) * 1536 + 768 + lcol_s;

  for (int kt = 0; kt < 12; ++kt) {
#pragma unroll
    for (int j = 0; j < 2; ++j) {
      gload_lds16(aptr[j], &As[(wid * 16 + j * 8) * 64]);
      aptr[j] += 64;
    }
#pragma unroll
    for (int j = 0; j < 4; ++j) {
      gload_lds16(bptr[j], &Bs[(wid * 32 + j * 8) * 64]);
      bptr[j] += 64;
    }
    __syncthreads();
    bf16x8 af[2][2], bfr[2][4];
#pragma unroll
    for (int kf = 0; kf < 2; ++kf)
#pragma unroll
      for (int mf = 0; mf < 2; ++mf)
        af[kf][mf] = *(const bf16x8*)&As[(wm * 32 + mf * 16 + (lane & 15)) * 64 + ((kf * 32 + (lane >> 4) * 8) ^ axor)];
#pragma unroll
    for (int kf = 0; kf < 2; ++kf)
#pragma unroll
      for (int nf = 0; nf < 4; ++nf)
        bfr[kf][nf] = *(const bf16x8*)&Bs[(wn * 64 + nf * 16 + (lane & 15)) * 64 + ((kf * 32 + (lane >> 4) * 8) ^ axor)];
#pragma unroll
    for (int mf = 0; mf < 2; ++mf)
#pragma unroll
      for (int nf = 0; nf < 4; ++nf) {
        acc[mf][nf] = __builtin_amdgcn_mfma_f32_16x16x32_bf16(af[0][mf], bfr[0][nf], acc[mf][nf], 0, 0, 0);
        acc[mf][nf] = __builtin_amdgcn_mfma_f32_16x16x32_bf16(af[1][mf], bfr[1][nf], acc[mf][nf], 0, 0, 0);
      }
    __syncthreads();
  }

  float* Hb = Ht + (size_t)b * 640 * DD;
#pragma unroll
  for (int mf = 0; mf < 2; ++mf)
#pragma unroll
    for (int nf = 0; nf < 4; ++nf)
#pragma unroll
      for (int r = 0; r < 4; ++r) {
        int row = m0 + wm * 32 + mf * 16 + (lane >> 4) * 4 + r;
        int col = n0 + wn * 64 + nf * 16 + (lane & 15);
        Hb[(size_t)row * DD + col] = acc[mf][nf][r];
      }
}

// ---------------- gemm_h: 128x96 tiles, single-buffer + fused score ----------------
__global__ __launch_bounds__(256, 3)
void gemm_h(const u16* __restrict__ Q, const float* __restrict__ Ht,
            const int* __restrict__ ids, const u16* __restrict__ Wcomb,
            const float* __restrict__ bf1x, const float* __restrict__ w2,
            const float* __restrict__ mask, float* __restrict__ out) {
  int flat = blockIdx.x;   // 1504 = 8*188
  int lid = (flat & 7) * 188 + (flat >> 3);
  int n = lid % 8;
  int m = (lid / 8) % 47;
  int b = lid / 376;

  const int m0 = m * 128;
  const int n0 = n * 96;
  const int tid = threadIdx.x;
  const int lane = tid & 63;
  const int wid = tid >> 6;
  const int wm = wid >> 1, wn = wid & 1;   // wave-tile 64x48

  __shared__ u16 As[128 * 64];
  __shared__ u16 Bs[96 * 64];
  __shared__ int sids[100];
  __shared__ float pacc[4];
  if (tid < 100) sids[tid] = ids[b * 100 + tid];
  if (tid < 4) pacc[tid] = 0.f;

  const u16* Abase = Q + (size_t)b * MPAD * DD;
  const u16* Bbase = Wcomb + (size_t)b * DD * DD;

  f32x4 acc[4][3] = {};

  const int lrow = lane >> 3;
  const int lcol_s = (((lane & 7) ^ (lrow & 7)) * 8);
  const int axor = (lane & 7) << 3;

  const u16* aptr[4];
  const u16* bptr[3];
#pragma unroll
  for (int j = 0; j < 4; ++j)
    aptr[j] = Abase + (size_t)(m0 + wid * 32 + j * 8 + lrow) * DD + lcol_s;
#pragma unroll
  for (int j = 0; j < 3; ++j)
    bptr[j] = Bbase + (size_t)(n0 + wid * 24 + j * 8 + lrow) * DD + lcol_s;

  for (int kt = 0; kt < 12; ++kt) {
#pragma unroll
    for (int j = 0; j < 4; ++j) {
      gload_lds16(aptr[j], &As[(wid * 32 + j * 8) * 64]);
      aptr[j] += 64;
    }
#pragma unroll
    for (int j = 0; j < 3; ++j) {
      gload_lds16(bptr[j], &Bs[(wid * 24 + j * 8) * 64]);
      bptr[j] += 64;
    }
    __syncthreads();
    bf16x8 af[2][4], bfr[2][3];
#pragma unroll
    for (int kf = 0; kf < 2; ++kf)
#pragma unroll
      for (int mf = 0; mf < 4; ++mf)
        af[kf][mf] = *(const bf16x8*)&As[(wm * 64 + mf * 16 + (lane & 15)) * 64 + ((kf * 32 + (lane >> 4) * 8) ^ axor)];
#pragma unroll
    for (int kf = 0; kf < 2; ++kf)
#pragma unroll
      for (int nf = 0; nf < 3; ++nf)
        bfr[kf][nf] = *(const bf16x8*)&Bs[(wn * 48 + nf * 16 + (lane & 15)) * 64 + ((kf * 32 + (lane >> 4) * 8) ^ axor)];
#pragma unroll
    for (int mf = 0; mf < 4; ++mf)
#pragma unroll
      for (int nf = 0; nf < 3; ++nf) {
        acc[mf][nf] = __builtin_amdgcn_mfma_f32_16x16x32_bf16(af[0][mf], bfr[0][nf], acc[mf][nf], 0, 0, 0);
        acc[mf][nf] = __builtin_amdgcn_mfma_f32_16x16x32_bf16(af[1][mf], bfr[1][nf], acc[mf][nf], 0, 0, 0);
      }
    __syncthreads();
  }

  // fused score epilogue: H = Hcore + Ht[gather] + bf1x[b]
  float b1v[3], w2v[3];
  int cbase = n0 + wn * 48 + (lane & 15);
#pragma unroll
  for (int nf = 0; nf < 3; ++nf) {
    b1v[nf] = bf1x[b * DD + cbase + nf * 16];
    w2v[nf] = w2[cbase + nf * 16];
  }
  const float* Hb = Ht + (size_t)b * 640 * DD;
  const int pfirst = m0 / 60;
#pragma unroll
  for (int mf = 0; mf < 4; ++mf)
#pragma unroll
    for (int r = 0; r < 4; ++r) {
      int row = m0 + wm * 64 + mf * 16 + (lane >> 4) * 4 + r;
      if (row < 6000) {
        int p = (unsigned)row / 60u;
        int tok = row - p * 60;
        const float* htrow = Hb + (size_t)(sids[p] * 60 + tok) * DD + cbase;
        float s = 0.f;
#pragma unroll
        for (int nf = 0; nf < 3; ++nf)
          s += fmaxf(acc[mf][nf][r] + htrow[nf * 16] + b1v[nf], 0.f) * w2v[nf];
        s += __shfl_xor(s, 1);
        s += __shfl_xor(s, 2);
        s += __shfl_xor(s, 4);
        s += __shfl_xor(s, 8);
        if ((lane & 15) == 0) {
          float mk = mask[((size_t)b * 100 + p) * 60 + tok];
          atomicAdd(&pacc[p - pfirst], mk * s);
        }
      }
    }
  __syncthreads();
  int plast = (m0 + 127 < 6000 ? m0 + 127 : 5999) / 60;
  if (tid <= plast - pfirst)
    atomicAdd(out + b * 100 + pfirst + tid, pacc[tid]);
}

// ---------------- launch ----------------
extern "C" void kernel_launch(void* const* d_in, const int* in_sizes, int n_in,
                              void* d_out, int out_size, void* d_ws, size_t ws_size,
                              hipStream_t stream) {
  const float* answer = (const float*)d_in[0];
  const float* qps    = (const float*)d_in[1];
  const float* mask   = (const float*)d_in[2];
  const int*   tids   = (const int*)d_in[3];
  const float* Wp     = (const float*)d_in[4];
  const float* bp     = (const float*)d_in[5];
  const float* Wt     = (const float*)d_in[6];
  const float* bt     = (const float*)d_in[7];
  const float* Wf1    = (const float*)d_in[8];
  const float* bf1    = (const float*)d_in[9];
  const float* Wf2    = (const float*)d_in[10];
  const float* bf2    = (const float*)d_in[11];
  float* out = (float*)d_out;

  char* ws = (char*)d_ws;
  // region layout (bytes); total ~102 MB
  u16* Qpad  = (u16*)(ws + 0);            // 36,962,304
  u16* ts    = (u16*)(ws + 36962304);     // 36,962,304
  u16* tmax  = (u16*)(ws + 73924608);     //  3,686,400
  float* Ht  = (float*)(ws + 77611008);   //  7,864,320
  u16* Wtb   = (u16*)(ws + 85475328);     //  4,718,592
  u16* WpbT  = (u16*)(ws + 90193920);     //  4,718,592
  u16* Wcomb = (u16*)(ws + 94912512);     //  4,718,592
  u16* Wf1b  = (u16*)(ws + 99631104);     //  2,359,296
  float* cp  = (float*)(ws + 101990400);  //     12,288
  float* ct  = (float*)(ws + 102002688);  //     12,288
  float* bf1x= (float*)(ws + 102014976);  //     12,288

  prep_all<<<12866, 256, 0, stream>>>(qps, (uint4*)Qpad, answer, Wp, Wt, Wtb, WpbT,
                                      Wf1, (uint4*)Wf1b, bp, bt, cp, ct,
                                      mask, bf2, out);

  mid_kernel<<<2040, 256, 0, stream>>>(Qpad, Wtb, ct, ts, Wf1b, WpbT, Wcomb,
                                       Wf1, cp, bf1, bf1x);

  table_max_kernel<<<720, 256, 0, stream>>>(ts, tids, tmax);

  gemm_t<<<240, 256, 0, stream>>>(tmax, Wf1b, Ht);

  gemm_h<<<1504, 256, 0, stream>>>(Qpad, Ht, tids, Wcomb, bf1x, Wf2, mask, out);
}

// Round 15
// 166.265 us; speedup vs baseline: 1.8860x; 1.0225x over previous
//
#include <hip/hip_runtime.h>
#include <hip/hip_bf16.h>

// FusionRetrModel: B=4, NL=2 (only l=1 used), P=100, TOK=60, T=6000, D=768.
// R15 pipeline (R14 + vectorized tmax + bf16 Ht):
//   prep_all: Qpad bf16; Wtb; WpbT; Wf1 cast; cp/ct GEMV; out init.
//   mid: [0,144) gemm_wc | [144,1272) gemm_ts | [1272,2040) prep2
//   tmax:   vectorized (uint2/4-col per thread, 240x192) per-table max
//   gemm_t: 64x128 tiles, 240 blocks; Ht stored bf16
//   gemm_h: 128x96 tiles, single-buffer; epilogue gathers bf16 Ht
// GEMMs: BK=64, single-buffer 32KB LDS (R13/R14: occupancy > dbuf at K=12),
// T2 swizzle (src-side), 0 bank conflicts. Workspace: ~98 MB.

typedef unsigned short u16;
typedef unsigned int u32;
typedef __attribute__((ext_vector_type(8))) short bf16x8;
typedef __attribute__((ext_vector_type(4))) float f32x4;

#define NUM_TABLES 10
#define MPAD 6016
#define DD 768

__device__ __forceinline__ u16 f2bf(float f) {
  u32 u = __builtin_bit_cast(u32, f);
  u32 r = u + 0x7FFFu + ((u >> 16) & 1u);
  return (u16)(r >> 16);
}
__device__ __forceinline__ float bf2f(u16 h) {
  u32 u = ((u32)h) << 16;
  return __builtin_bit_cast(float, u);
}
__device__ __forceinline__ u32 pack_bf2(float lo, float hi) {
  return (u32)f2bf(lo) | ((u32)f2bf(hi) << 16);
}

__device__ __forceinline__ void gload_lds16(const u16* g, u16* l) {
  __builtin_amdgcn_global_load_lds(
      (const __attribute__((address_space(1))) void*)g,
      (__attribute__((address_space(3))) void*)l, 16, 0, 0);
}

// ---------------- fused prep (one dispatch) ----------------
__global__ void prep_all(const float* __restrict__ qps, uint4* __restrict__ qpad,
                         const float* __restrict__ Ans, const float* __restrict__ Wp,
                         const float* __restrict__ Wt, u16* __restrict__ Wtb,
                         u16* __restrict__ WpbT,
                         const float* __restrict__ Wf1, uint4* __restrict__ Wf1b,
                         const float* __restrict__ bp, const float* __restrict__ bt,
                         float* __restrict__ cp, float* __restrict__ ct,
                         const float* __restrict__ mask, const float* __restrict__ bf2,
                         float* __restrict__ out) {
  int blk = blockIdx.x;
  int tid = threadIdx.x;
  if (blk < 9024) {
    // ---- Qpad: cast l=1 slice to bf16, pad rows [6000,6016) ----
    size_t c = (size_t)blk * 256 + tid;
    const int per_b = MPAD * (DD / 8);
    int b = (int)(c / per_b);
    int rr = (int)(c % per_b);
    int r = rr / (DD / 8);
    int kc = rr % (DD / 8);
    uint4 o;
    if (r < 6000) {
      const float* src = qps + (((size_t)(b * 2 + 1)) * 6000 + r) * DD + kc * 8;
      float4 f0 = *(const float4*)src;
      float4 f1 = *(const float4*)(src + 4);
      o.x = pack_bf2(f0.x, f0.y);
      o.y = pack_bf2(f0.z, f0.w);
      o.z = pack_bf2(f1.x, f1.y);
      o.w = pack_bf2(f1.z, f1.w);
    } else {
      o = make_uint4(0, 0, 0, 0);
    }
    qpad[c] = o;
  } else if (blk < 10176) {
    // ---- Wtb[b][d][k] = Wt[d][768+k] + A[b][k]*Wt[d][1536+k] ----
    size_t c = (size_t)(blk - 9024) * 256 + tid;
    const int per_b = DD * (DD / 8);
    int b = (int)(c / per_b);
    int rr = (int)(c % per_b);
    int d = rr / (DD / 8);
    int k8 = (rr % (DD / 8)) * 8;
    const float* a = Ans + ((size_t)b * 2 + 1) * DD + k8;
    const float* w2r = Wt + (size_t)d * 2304 + 768 + k8;
    const float* w3r = Wt + (size_t)d * 2304 + 1536 + k8;
    float4 a0 = *(const float4*)a, a1 = *(const float4*)(a + 4);
    float4 t20 = *(const float4*)w2r, t21 = *(const float4*)(w2r + 4);
    float4 t30 = *(const float4*)w3r, t31 = *(const float4*)(w3r + 4);
    uint4 o;
    o.x = pack_bf2(t20.x + a0.x * t30.x, t20.y + a0.y * t30.y);
    o.y = pack_bf2(t20.z + a0.z * t30.z, t20.w + a0.w * t30.w);
    o.z = pack_bf2(t21.x + a1.x * t31.x, t21.y + a1.y * t31.y);
    o.w = pack_bf2(t21.z + a1.z * t31.z, t21.w + a1.w * t31.w);
    *(uint4*)(Wtb + ((size_t)b * DD + d) * DD + k8) = o;
  } else if (blk < 10752) {
    // ---- WpbT[b][k][d] = Wp[d][768+k] + A[b][k]*Wp[d][1536+k] (LDS transpose) ----
    int tb = blk - 10176;
    int b = tb / 144;
    int tt = tb % 144;
    int k0 = (tt / 12) * 64, d0 = (tt % 12) * 64;
    __shared__ u16 tile[64][72];
    int kc = tid & 63;
    int r0 = tid >> 6;
    float av = Ans[((size_t)b * 2 + 1) * DD + k0 + kc];
#pragma unroll
    for (int it = 0; it < 16; ++it) {
      int dr = it * 4 + r0;
      const float* wrow = Wp + (size_t)(d0 + dr) * 2304;
      float v = wrow[768 + k0 + kc] + av * wrow[1536 + k0 + kc];
      tile[kc][dr] = f2bf(v);
    }
    __syncthreads();
#pragma unroll
    for (int it = 0; it < 2; ++it) {
      int kk = it * 32 + (tid >> 3);
      int dd = (tid & 7) * 8;
      *(uint4*)(WpbT + ((size_t)b * DD + k0 + kk) * DD + d0 + dd) =
          *(const uint4*)&tile[kk][dd];
    }
  } else if (blk < 11328) {
    // ---- Wf1 cast ----
    size_t c = (size_t)(blk - 10752) * 256 + tid;
    const float* src = Wf1 + c * 8;
    float4 f0 = *(const float4*)src;
    float4 f1 = *(const float4*)(src + 4);
    uint4 o;
    o.x = pack_bf2(f0.x, f0.y);
    o.y = pack_bf2(f0.z, f0.w);
    o.z = pack_bf2(f1.x, f1.y);
    o.w = pack_bf2(f1.z, f1.w);
    Wf1b[c] = o;
  } else if (blk < 12864) {
    // ---- cp/ct parallel: one block per (matrix, d) ----
    int e = blk - 11328;
    int isT = e >= 768;
    int d = e - (isT ? 768 : 0);
    const float* wrow = (isT ? Wt : Wp) + (size_t)d * 2304;
    float a0 = 0.f, a1 = 0.f, a2 = 0.f, a3 = 0.f;
    for (int k = tid; k < DD; k += 256) {
      float w = wrow[k];
      a0 += w * Ans[1 * DD + k];
      a1 += w * Ans[3 * DD + k];
      a2 += w * Ans[5 * DD + k];
      a3 += w * Ans[7 * DD + k];
    }
#pragma unroll
    for (int off = 32; off > 0; off >>= 1) {
      a0 += __shfl_down(a0, off);
      a1 += __shfl_down(a1, off);
      a2 += __shfl_down(a2, off);
      a3 += __shfl_down(a3, off);
    }
    __shared__ float red[4][4];
    int wid = tid >> 6;
    if ((tid & 63) == 0) {
      red[wid][0] = a0; red[wid][1] = a1; red[wid][2] = a2; red[wid][3] = a3;
    }
    __syncthreads();
    if (tid < 4) {
      float s = red[0][tid] + red[1][tid] + red[2][tid] + red[3][tid];
      float bias = (isT ? bt : bp)[d];
      (isT ? ct : cp)[tid * DD + d] = s + bias;
    }
  } else {
    // ---- out init = bf2 * msum ----
    int idx = (blk - 12864) * 256 + tid;
    if (idx >= 400) return;
    const float* m = mask + (size_t)idx * 60;
    float s = 0.f;
    for (int t = 0; t < 60; ++t) s += m[t];
    out[idx] = bf2[0] * s;
  }
}

// ---------------- mid: gemm_wc | gemm_ts | prep2 (single-buffer LDS) ----------------
__global__ __launch_bounds__(256, 3)
void mid_kernel(const u16* __restrict__ Q, const u16* __restrict__ Wtb,
                const float* __restrict__ ct, u16* __restrict__ ts,
                const u16* __restrict__ Wf1b, const u16* __restrict__ WpbT,
                u16* __restrict__ Wcomb, const float* __restrict__ Wf1,
                const float* __restrict__ cp, const float* __restrict__ bf1,
                float* __restrict__ bf1x) {
  __shared__ u16 As[128 * 64];
  __shared__ u16 Bs[128 * 64];
  __shared__ float red[4][4];
  int blk = blockIdx.x;
  int tid = threadIdx.x;

  if (blk >= 1272) {
    // ---- prep2: bf1x[b][c] = bf1[c] + Wf1_lo[c,:].cp[b,:] ----
    int c = blk - 1272;
    const float* wrow = Wf1 + (size_t)c * 1536;
    float a0 = 0.f, a1 = 0.f, a2 = 0.f, a3 = 0.f;
    for (int d = tid; d < DD; d += 256) {
      float w = wrow[d];
      a0 += w * cp[0 * DD + d];
      a1 += w * cp[1 * DD + d];
      a2 += w * cp[2 * DD + d];
      a3 += w * cp[3 * DD + d];
    }
#pragma unroll
    for (int off = 32; off > 0; off >>= 1) {
      a0 += __shfl_down(a0, off);
      a1 += __shfl_down(a1, off);
      a2 += __shfl_down(a2, off);
      a3 += __shfl_down(a3, off);
    }
    int wid = tid >> 6;
    if ((tid & 63) == 0) {
      red[wid][0] = a0; red[wid][1] = a1; red[wid][2] = a2; red[wid][3] = a3;
    }
    __syncthreads();
    if (tid < 4) {
      float s = red[0][tid] + red[1][tid] + red[2][tid] + red[3][tid];
      bf1x[tid * DD + c] = bf1[c] + s;
    }
    return;
  }

  const int lane = tid & 63;
  const int wid = tid >> 6;
  const int wm = wid >> 1, wn = wid & 1;
  const int lrow = lane >> 3;
  const int lcol_s = (((lane & 7) ^ (lrow & 7)) * 8);
  const int axor = (lane & 7) << 3;
  f32x4 acc[4][4] = {};

  if (blk >= 144) {
    // ---- gemm_ts: ts = Qpad @ Wtb^T + ct ----
    int g = blk - 144;
    int lid = (g & 7) * 141 + (g >> 3);
    int n = lid % 6;
    int m = (lid / 6) % 47;
    int b = lid / 282;
    const int m0 = m * 128;
    const int n0 = n * 128;

    const u16* Abase = Q + (size_t)b * MPAD * DD;
    const u16* Bbase = Wtb + (size_t)b * DD * DD;

    const u16* aptr[4];
    const u16* bptr[4];
#pragma unroll
    for (int j = 0; j < 4; ++j) {
      aptr[j] = Abase + (size_t)(m0 + wid * 32 + j * 8 + lrow) * DD + lcol_s;
      bptr[j] = Bbase + (size_t)(n0 + wid * 32 + j * 8 + lrow) * DD + lcol_s;
    }

    for (int kt = 0; kt < 12; ++kt) {
#pragma unroll
      for (int j = 0; j < 4; ++j) {
        gload_lds16(aptr[j], &As[(wid * 32 + j * 8) * 64]);
        gload_lds16(bptr[j], &Bs[(wid * 32 + j * 8) * 64]);
        aptr[j] += 64; bptr[j] += 64;
      }
      __syncthreads();
      bf16x8 af[2][4], bfr[2][4];
#pragma unroll
      for (int kf = 0; kf < 2; ++kf)
#pragma unroll
        for (int mf = 0; mf < 4; ++mf)
          af[kf][mf] = *(const bf16x8*)&As[(wm * 64 + mf * 16 + (lane & 15)) * 64 + ((kf * 32 + (lane >> 4) * 8) ^ axor)];
#pragma unroll
      for (int kf = 0; kf < 2; ++kf)
#pragma unroll
        for (int nf = 0; nf < 4; ++nf)
          bfr[kf][nf] = *(const bf16x8*)&Bs[(wn * 64 + nf * 16 + (lane & 15)) * 64 + ((kf * 32 + (lane >> 4) * 8) ^ axor)];
#pragma unroll
      for (int mf = 0; mf < 4; ++mf)
#pragma unroll
        for (int nf = 0; nf < 4; ++nf) {
          acc[mf][nf] = __builtin_amdgcn_mfma_f32_16x16x32_bf16(af[0][mf], bfr[0][nf], acc[mf][nf], 0, 0, 0);
          acc[mf][nf] = __builtin_amdgcn_mfma_f32_16x16x32_bf16(af[1][mf], bfr[1][nf], acc[mf][nf], 0, 0, 0);
        }
      __syncthreads();
    }

    u16* dst = ts + (size_t)b * MPAD * DD;
    const float* cv = ct + b * DD;
#pragma unroll
    for (int mf = 0; mf < 4; ++mf)
#pragma unroll
      for (int nf = 0; nf < 4; ++nf)
#pragma unroll
        for (int r = 0; r < 4; ++r) {
          int row = m0 + wm * 64 + mf * 16 + (lane >> 4) * 4 + r;
          int col = n0 + wn * 64 + nf * 16 + (lane & 15);
          dst[(size_t)row * DD + col] = f2bf(acc[mf][nf][r] + cv[col]);
        }
  } else {
    // ---- gemm_wc: Wcomb[b][c][k] = sum_d Wf1_lo[c][d] * WpbT[b][k][d] ----
    int f = blk;
    int lid = (f & 7) * 18 + (f >> 3);
    int n = lid % 6;
    int m = (lid / 6) % 6;
    int b = lid / 36;
    const int m0 = m * 128;
    const int n0 = n * 128;

    const u16* Bbase = WpbT + (size_t)b * DD * DD;
    const u16* aptr[4];
    const u16* bptr[4];
#pragma unroll
    for (int j = 0; j < 4; ++j) {
      aptr[j] = Wf1b + (size_t)(m0 + wid * 32 + j * 8 + lrow) * 1536 + lcol_s;
      bptr[j] = Bbase + (size_t)(n0 + wid * 32 + j * 8 + lrow) * DD + lcol_s;
    }

    for (int kt = 0; kt < 12; ++kt) {
#pragma unroll
      for (int j = 0; j < 4; ++j) {
        gload_lds16(aptr[j], &As[(wid * 32 + j * 8) * 64]);
        gload_lds16(bptr[j], &Bs[(wid * 32 + j * 8) * 64]);
        aptr[j] += 64; bptr[j] += 64;
      }
      __syncthreads();
      bf16x8 af[2][4], bfr[2][4];
#pragma unroll
      for (int kf = 0; kf < 2; ++kf)
#pragma unroll
        for (int mf = 0; mf < 4; ++mf)
          af[kf][mf] = *(const bf16x8*)&As[(wm * 64 + mf * 16 + (lane & 15)) * 64 + ((kf * 32 + (lane >> 4) * 8) ^ axor)];
#pragma unroll
      for (int kf = 0; kf < 2; ++kf)
#pragma unroll
        for (int nf = 0; nf < 4; ++nf)
          bfr[kf][nf] = *(const bf16x8*)&Bs[(wn * 64 + nf * 16 + (lane & 15)) * 64 + ((kf * 32 + (lane >> 4) * 8) ^ axor)];
#pragma unroll
      for (int mf = 0; mf < 4; ++mf)
#pragma unroll
        for (int nf = 0; nf < 4; ++nf) {
          acc[mf][nf] = __builtin_amdgcn_mfma_f32_16x16x32_bf16(af[0][mf], bfr[0][nf], acc[mf][nf], 0, 0, 0);
          acc[mf][nf] = __builtin_amdgcn_mfma_f32_16x16x32_bf16(af[1][mf], bfr[1][nf], acc[mf][nf], 0, 0, 0);
        }
      __syncthreads();
    }

    u16* Cb = Wcomb + (size_t)b * DD * DD;
#pragma unroll
    for (int mf = 0; mf < 4; ++mf)
#pragma unroll
      for (int nf = 0; nf < 4; ++nf)
#pragma unroll
        for (int r = 0; r < 4; ++r) {
          int row = m0 + wm * 64 + mf * 16 + (lane >> 4) * 4 + r;
          int col = n0 + wn * 64 + nf * 16 + (lane & 15);
          Cb[(size_t)row * DD + col] = f2bf(acc[mf][nf][r]);
        }
  }
}

// ---------------- table max (vectorized: 4 cols/thread via uint2) ----------------
__global__ __launch_bounds__(192)
void table_max_kernel(const u16* __restrict__ ts, const int* __restrict__ ids,
                      u16* __restrict__ tmax) {
  int bi = blockIdx.x;  // 240 = 4*60
  int b = bi / 60;
  int tok = bi % 60;
  int c4 = threadIdx.x * 4;   // 192 threads x 4 cols = 768
  __shared__ int sids[100];
  if (threadIdx.x < 100) sids[threadIdx.x] = ids[b * 100 + threadIdx.x];
  __syncthreads();
  float m0[NUM_TABLES], m1[NUM_TABLES], m2[NUM_TABLES], m3[NUM_TABLES];
#pragma unroll
  for (int t = 0; t < NUM_TABLES; ++t) {
    m0[t] = -INFINITY; m1[t] = -INFINITY; m2[t] = -INFINITY; m3[t] = -INFINITY;
  }
  const u16* base = ts + ((size_t)b * MPAD + tok) * DD + c4;
  for (int p = 0; p < 100; ++p) {
    uint2 v = *(const uint2*)(base + (size_t)p * 60 * DD);
    float v0 = bf2f((u16)(v.x & 0xFFFF));
    float v1 = bf2f((u16)(v.x >> 16));
    float v2 = bf2f((u16)(v.y & 0xFFFF));
    float v3 = bf2f((u16)(v.y >> 16));
    int id = sids[p];
#pragma unroll
    for (int t = 0; t < NUM_TABLES; ++t)
      if (id == t) {
        m0[t] = fmaxf(m0[t], v0);
        m1[t] = fmaxf(m1[t], v1);
        m2[t] = fmaxf(m2[t], v2);
        m3[t] = fmaxf(m3[t], v3);
      }
  }
#pragma unroll
  for (int t = 0; t < NUM_TABLES; ++t) {
    uint2 o;
    o.x = pack_bf2(m0[t], m1[t]);
    o.y = pack_bf2(m2[t], m3[t]);
    *(uint2*)(tmax + (((size_t)b * NUM_TABLES + t) * 60 + tok) * DD + c4) = o;
  }
}

// ---------------- gemm_t: 64x128 tiles, 240 blocks, single-buffer; Ht bf16 ----------------
__global__ __launch_bounds__(256, 3)
void gemm_t(const u16* __restrict__ tmax, const u16* __restrict__ Wf1b,
            u16* __restrict__ Ht) {
  int flat = blockIdx.x;   // 240 = 8*30
  int lid = (flat & 7) * 30 + (flat >> 3);
  int n = lid % 6;
  int m = (lid / 6) % 10;
  int b = lid / 60;

  const int m0 = m * 64;
  const int n0 = n * 128;
  const int tid = threadIdx.x;
  const int lane = tid & 63;
  const int wid = tid >> 6;
  const int wm = wid >> 1, wn = wid & 1;   // wave-tile 32x64

  __shared__ u16 As[64 * 64];
  __shared__ u16 Bs[128 * 64];

  const u16* Abase = tmax + (size_t)b * 600 * DD;

  f32x4 acc[2][4] = {};

  const int lrow = lane >> 3;
  const int lcol_s = (((lane & 7) ^ (lrow & 7)) * 8);
  const int axor = (lane & 7) << 3;

  const u16* aptr[2];
  const u16* bptr[4];
#pragma unroll
  for (int j = 0; j < 2; ++j) {
    int row = m0 + wid * 16 + j * 8 + lrow;
    int rp = row < 600 ? row : 599;
    aptr[j] = Abase + (size_t)rp * DD + lcol_s;
  }
#pragma unroll
  for (int j = 0; j < 4; ++j)
    bptr[j] = Wf1b + (size_t)(n0 + wid * 32 + j * 8 + lrow) * 1536 + 768 + lcol_s;

  for (int kt = 0; kt < 12; ++kt) {
#pragma unroll
    for (int j = 0; j < 2; ++j) {
      gload_lds16(aptr[j], &As[(wid * 16 + j * 8) * 64]);
      aptr[j] += 64;
    }
#pragma unroll
    for (int j = 0; j < 4; ++j) {
      gload_lds16(bptr[j], &Bs[(wid * 32 + j * 8) * 64]);
      bptr[j] += 64;
    }
    __syncthreads();
    bf16x8 af[2][2], bfr[2][4];
#pragma unroll
    for (int kf = 0; kf < 2; ++kf)
#pragma unroll
      for (int mf = 0; mf < 2; ++mf)
        af[kf][mf] = *(const bf16x8*)&As[(wm * 32 + mf * 16 + (lane & 15)) * 64 + ((kf * 32 + (lane >> 4) * 8) ^ axor)];
#pragma unroll
    for (int kf = 0; kf < 2; ++kf)
#pragma unroll
      for (int nf = 0; nf < 4; ++nf)
        bfr[kf][nf] = *(const bf16x8*)&Bs[(wn * 64 + nf * 16 + (lane & 15)) * 64 + ((kf * 32 + (lane >> 4) * 8) ^ axor)];
#pragma unroll
    for (int mf = 0; mf < 2; ++mf)
#pragma unroll
      for (int nf = 0; nf < 4; ++nf) {
        acc[mf][nf] = __builtin_amdgcn_mfma_f32_16x16x32_bf16(af[0][mf], bfr[0][nf], acc[mf][nf], 0, 0, 0);
        acc[mf][nf] = __builtin_amdgcn_mfma_f32_16x16x32_bf16(af[1][mf], bfr[1][nf], acc[mf][nf], 0, 0, 0);
      }
    __syncthreads();
  }

  u16* Hb = Ht + (size_t)b * 640 * DD;
#pragma unroll
  for (int mf = 0; mf < 2; ++mf)
#pragma unroll
    for (int nf = 0; nf < 4; ++nf)
#pragma unroll
      for (int r = 0; r < 4; ++r) {
        int row = m0 + wm * 32 + mf * 16 + (lane >> 4) * 4 + r;
        int col = n0 + wn * 64 + nf * 16 + (lane & 15);
        Hb[(size_t)row * DD + col] = f2bf(acc[mf][nf][r]);
      }
}

// ---------------- gemm_h: 128x96 tiles, single-buffer + fused score ----------------
__global__ __launch_bounds__(256, 3)
void gemm_h(const u16* __restrict__ Q, const u16* __restrict__ Ht,
            const int* __restrict__ ids, const u16* __restrict__ Wcomb,
            const float* __restrict__ bf1x, const float* __restrict__ w2,
            const float* __restrict__ mask, float* __restrict__ out) {
  int flat = blockIdx.x;   // 1504 = 8*188
  int lid = (flat & 7) * 188 + (flat >> 3);
  int n = lid % 8;
  int m = (lid / 8) % 47;
  int b = lid / 376;

  const int m0 = m * 128;
  const int n0 = n * 96;
  const int tid = threadIdx.x;
  const int lane = tid & 63;
  const int wid = tid >> 6;
  const int wm = wid >> 1, wn = wid & 1;   // wave-tile 64x48

  __shared__ u16 As[128 * 64];
  __shared__ u16 Bs[96 * 64];
  __shared__ int sids[100];
  __shared__ float pacc[4];
  if (tid < 100) sids[tid] = ids[b * 100 + tid];
  if (tid < 4) pacc[tid] = 0.f;

  const u16* Abase = Q + (size_t)b * MPAD * DD;
  const u16* Bbase = Wcomb + (size_t)b * DD * DD;

  f32x4 acc[4][3] = {};

  const int lrow = lane >> 3;
  const int lcol_s = (((lane & 7) ^ (lrow & 7)) * 8);
  const int axor = (lane & 7) << 3;

  const u16* aptr[4];
  const u16* bptr[3];
#pragma unroll
  for (int j = 0; j < 4; ++j)
    aptr[j] = Abase + (size_t)(m0 + wid * 32 + j * 8 + lrow) * DD + lcol_s;
#pragma unroll
  for (int j = 0; j < 3; ++j)
    bptr[j] = Bbase + (size_t)(n0 + wid * 24 + j * 8 + lrow) * DD + lcol_s;

  for (int kt = 0; kt < 12; ++kt) {
#pragma unroll
    for (int j = 0; j < 4; ++j) {
      gload_lds16(aptr[j], &As[(wid * 32 + j * 8) * 64]);
      aptr[j] += 64;
    }
#pragma unroll
    for (int j = 0; j < 3; ++j) {
      gload_lds16(bptr[j], &Bs[(wid * 24 + j * 8) * 64]);
      bptr[j] += 64;
    }
    __syncthreads();
    bf16x8 af[2][4], bfr[2][3];
#pragma unroll
    for (int kf = 0; kf < 2; ++kf)
#pragma unroll
      for (int mf = 0; mf < 4; ++mf)
        af[kf][mf] = *(const bf16x8*)&As[(wm * 64 + mf * 16 + (lane & 15)) * 64 + ((kf * 32 + (lane >> 4) * 8) ^ axor)];
#pragma unroll
    for (int kf = 0; kf < 2; ++kf)
#pragma unroll
      for (int nf = 0; nf < 3; ++nf)
        bfr[kf][nf] = *(const bf16x8*)&Bs[(wn * 48 + nf * 16 + (lane & 15)) * 64 + ((kf * 32 + (lane >> 4) * 8) ^ axor)];
#pragma unroll
    for (int mf = 0; mf < 4; ++mf)
#pragma unroll
      for (int nf = 0; nf < 3; ++nf) {
        acc[mf][nf] = __builtin_amdgcn_mfma_f32_16x16x32_bf16(af[0][mf], bfr[0][nf], acc[mf][nf], 0, 0, 0);
        acc[mf][nf] = __builtin_amdgcn_mfma_f32_16x16x32_bf16(af[1][mf], bfr[1][nf], acc[mf][nf], 0, 0, 0);
      }
    __syncthreads();
  }

  // fused score epilogue: H = Hcore + Ht[gather](bf16) + bf1x[b]
  float b1v[3], w2v[3];
  int cbase = n0 + wn * 48 + (lane & 15);
#pragma unroll
  for (int nf = 0; nf < 3; ++nf) {
    b1v[nf] = bf1x[b * DD + cbase + nf * 16];
    w2v[nf] = w2[cbase + nf * 16];
  }
  const u16* Hb = Ht + (size_t)b * 640 * DD;
  const int pfirst = m0 / 60;
#pragma unroll
  for (int mf = 0; mf < 4; ++mf)
#pragma unroll
    for (int r = 0; r < 4; ++r) {
      int row = m0 + wm * 64 + mf * 16 + (lane >> 4) * 4 + r;
      if (row < 6000) {
        int p = (unsigned)row / 60u;
        int tok = row - p * 60;
        const u16* htrow = Hb + (size_t)(sids[p] * 60 + tok) * DD + cbase;
        float s = 0.f;
#pragma unroll
        for (int nf = 0; nf < 3; ++nf)
          s += fmaxf(acc[mf][nf][r] + bf2f(htrow[nf * 16]) + b1v[nf], 0.f) * w2v[nf];
        s += __shfl_xor(s, 1);
        s += __shfl_xor(s, 2);
        s += __shfl_xor(s, 4);
        s += __shfl_xor(s, 8);
        if ((lane & 15) == 0) {
          float mk = mask[((size_t)b * 100 + p) * 60 + tok];
          atomicAdd(&pacc[p - pfirst], mk * s);
        }
      }
    }
  __syncthreads();
  int plast = (m0 + 127 < 6000 ? m0 + 127 : 5999) / 60;
  if (tid <= plast - pfirst)
    atomicAdd(out + b * 100 + pfirst + tid, pacc[tid]);
}

// ---------------- launch ----------------
extern "C" void kernel_launch(void* const* d_in, const int* in_sizes, int n_in,
                              void* d_out, int out_size, void* d_ws, size_t ws_size,
                              hipStream_t stream) {
  const float* answer = (const float*)d_in[0];
  const float* qps    = (const float*)d_in[1];
  const float* mask   = (const float*)d_in[2];
  const int*   tids   = (const int*)d_in[3];
  const float* Wp     = (const float*)d_in[4];
  const float* bp     = (const float*)d_in[5];
  const float* Wt     = (const float*)d_in[6];
  const float* bt     = (const float*)d_in[7];
  const float* Wf1    = (const float*)d_in[8];
  const float* bf1    = (const float*)d_in[9];
  const float* Wf2    = (const float*)d_in[10];
  const float* bf2    = (const float*)d_in[11];
  float* out = (float*)d_out;

  char* ws = (char*)d_ws;
  // region layout (bytes); total ~98 MB
  u16* Qpad  = (u16*)(ws + 0);            // 36,962,304
  u16* ts    = (u16*)(ws + 36962304);     // 36,962,304
  u16* tmax  = (u16*)(ws + 73924608);     //  3,686,400
  u16* Ht    = (u16*)(ws + 77611008);     //  3,932,160 ([4][640][768] bf16)
  u16* Wtb   = (u16*)(ws + 81543168);     //  4,718,592
  u16* WpbT  = (u16*)(ws + 86261760);     //  4,718,592
  u16* Wcomb = (u16*)(ws + 90980352);     //  4,718,592
  u16* Wf1b  = (u16*)(ws + 95698944);     //  2,359,296
  float* cp  = (float*)(ws + 98058240);   //     12,288
  float* ct  = (float*)(ws + 98070528);   //     12,288
  float* bf1x= (float*)(ws + 98082816);   //     12,288

  prep_all<<<12866, 256, 0, stream>>>(qps, (uint4*)Qpad, answer, Wp, Wt, Wtb, WpbT,
                                      Wf1, (uint4*)Wf1b, bp, bt, cp, ct,
                                      mask, bf2, out);

  mid_kernel<<<2040, 256, 0, stream>>>(Qpad, Wtb, ct, ts, Wf1b, WpbT, Wcomb,
                                       Wf1, cp, bf1, bf1x);

  table_max_kernel<<<240, 192, 0, stream>>>(ts, tids, tmax);

  gemm_t<<<240, 256, 0, stream>>>(tmax, Wf1b, Ht);

  gemm_h<<<1504, 256, 0, stream>>>(Qpad, Ht, tids, Wcomb, bf1x, Wf2, mask, out);
}